// Round 10
// baseline (440.465 us; speedup 1.0000x reference)
//
#include <hip/hip_runtime.h>
#include <hip/hip_bf16.h>

#define NF 100000
#define TM 64
#define NB 1563   // ceil(NF/TM)

typedef __attribute__((ext_vector_type(8))) short bf16x8;
typedef __attribute__((ext_vector_type(4))) short bf16x4;
typedef __attribute__((ext_vector_type(4))) float f32x4;

__device__ __forceinline__ short bfs(float x) {
    union { __hip_bfloat16 h; short s; } u;
    u.h = __float2bfloat16(x);
    return u.s;
}

__device__ __forceinline__ float b2f(short s) {
    union { float f; unsigned u; } u;
    u.u = ((unsigned)(unsigned short)s) << 16;
    return u.f;
}

__device__ __forceinline__ bf16x8 cvt8(const float4 a, const float4 b) {
    bf16x8 r;
    r[0] = bfs(a.x); r[1] = bfs(a.y); r[2] = bfs(a.z); r[3] = bfs(a.w);
    r[4] = bfs(b.x); r[5] = bfs(b.y); r[6] = bfs(b.z); r[7] = bfs(b.w);
    return r;
}

__device__ __forceinline__ float mish_f(float v) {
    float t = __expf(v);
    float p = t * (t + 2.0f);
    float r = v * p * __builtin_amdgcn_rcpf(p + 2.0f);
    return (v > 20.0f) ? v : r;
}

// ---- fp32 -> bf16 pre-conversion ----
__global__ __launch_bounds__(256)
void cvt_emb(const float* __restrict__ in, __hip_bfloat16* __restrict__ out) {
    long e = ((long)blockIdx.x * 256 + threadIdx.x) * 8;
    const float4* s = (const float4*)(in + e);
    *(bf16x8*)(out + e) = cvt8(s[0], s[1]);
}

struct CvtW {
    const float* src[8];
    long pre[9];
};

__global__ __launch_bounds__(256)
void cvt_w(CvtW a, __hip_bfloat16* __restrict__ dst) {
    long e = ((long)blockIdx.x * 256 + threadIdx.x) * 8;
    if (e >= a.pre[8]) return;
    int k = 0;
    #pragma unroll
    for (int j = 0; j < 8; j++) if (e >= a.pre[j + 1]) k = j + 1;
    const float4* s = (const float4*)(a.src[k] + (e - a.pre[k]));
    *(bf16x8*)(dst + e) = cvt8(s[0], s[1]);
}

// ---- main kernel: GEMM1 fed DIRECTLY from global emb (no X staging) ----
// Swapped MFMA (A=weight frag, B=fact frag). B-frag for 16x16x32 = 16B/lane at
// emb[node*64 + k-offset] -- exactly the gather granule, so no LDS X buffer and
// only ONE barrier per block (H exchange between GEMM1 and GEMM2).
// seg index ks>>1 and residual seg (c0+ct*16)>>6 are static/kg-invariant ->
// nd[][] stays in registers (no scratch).
template<int D, int A, int MINW>
__global__ __launch_bounds__(256, MINW)
void msg2_kernel(const __hip_bfloat16* __restrict__ emb,
                 const int* __restrict__ idx,
                 const __hip_bfloat16* __restrict__ wi, const float* __restrict__ bi,
                 const __hip_bfloat16* __restrict__ wo, const float* __restrict__ bo,
                 float* __restrict__ out_msgs, float* __restrict__ out_idx)
{
    constexpr int DP = D + 8;     // H row stride: conflict-benign ds_read_b128
    constexpr int CT = D / 64;
    constexpr int KS = D / 32;
    __shared__ __hip_bfloat16 buf[TM][DP];   // H only

    const int g    = blockIdx.y;
    const int f0   = blockIdx.x * TM;
    const int tid  = threadIdx.x;
    const int lane = tid & 63;
    const int w    = tid >> 6;
    const long gFA = (long)g * NF * A;
    const int valid = min(TM, NF - f0);
    const int* idx_g = idx + gFA + (long)f0 * A;

    // indices output (independent, issue early)
    if (tid < valid * A) out_idx[gFA + (long)f0 * A + tid] = (float)idx_g[tid];

    const int ar = lane & 15;
    const int kg = lane >> 4;
    const int c0 = w * (D / 4);
    const long wbase = (long)g * D * D;

    // per-lane clamped facts + node ids (4 fact-tiles x A segments, static-indexed)
    int fcl[4];
    int nd[4][A];
    #pragma unroll
    for (int rt = 0; rt < 4; rt++) {
        fcl[rt] = min(rt * 16 + ar, valid - 1);
        #pragma unroll
        for (int s = 0; s < A; s++) nd[rt][s] = idx_g[fcl[rt] * A + s];
    }

    f32x4 acc[4][CT];
    #pragma unroll
    for (int rt = 0; rt < 4; rt++)
        #pragma unroll
        for (int ct = 0; ct < CT; ct++) acc[rt][ct] = (f32x4)0.0f;

    // ---- GEMM1: Wi x X^T, B-frags straight from global ----
    #pragma unroll
    for (int ks = 0; ks < KS; ks++) {
        const int koff = (ks & 1) * 32 + kg * 8;       // offset within 64-elem segment
        bf16x8 xb[4];
        #pragma unroll
        for (int rt = 0; rt < 4; rt++)
            xb[rt] = *(const bf16x8*)(emb + (long)nd[rt][ks >> 1] * 64 + koff);
        #pragma unroll
        for (int ct = 0; ct < CT; ct++) {
            bf16x8 wf = *(const bf16x8*)(wi + wbase + (long)(c0 + ct * 16 + ar) * D + ks * 32 + kg * 8);
            #pragma unroll
            for (int rt = 0; rt < 4; rt++)
                acc[rt][ct] = __builtin_amdgcn_mfma_f32_16x16x32_bf16(wf, xb[rt], acc[rt][ct], 0, 0, 0);
        }
    }

    // ---- epilogue 1: bias + mish -> buf (H); no barrier needed before writes ----
    #pragma unroll
    for (int ct = 0; ct < CT; ct++) {
        const int cb = c0 + ct * 16 + kg * 4;
        const float4 bi4 = *(const float4*)(bi + g * D + cb);
        #pragma unroll
        for (int rt = 0; rt < 4; rt++) {
            bf16x4 hv;
            hv[0] = bfs(mish_f(acc[rt][ct][0] + bi4.x));
            hv[1] = bfs(mish_f(acc[rt][ct][1] + bi4.y));
            hv[2] = bfs(mish_f(acc[rt][ct][2] + bi4.z));
            hv[3] = bfs(mish_f(acc[rt][ct][3] + bi4.w));
            *(bf16x4*)(&buf[rt * 16 + ar][cb]) = hv;
        }
    }
    __syncthreads();   // the block's single barrier: H fully written

    // ---- GEMM2: Wo x H^T (H from LDS) ----
    #pragma unroll
    for (int rt = 0; rt < 4; rt++)
        #pragma unroll
        for (int ct = 0; ct < CT; ct++) acc[rt][ct] = (f32x4)0.0f;

    #pragma unroll
    for (int ks = 0; ks < KS; ks++) {
        const int kk = ks * 32;
        bf16x8 hb[4];
        #pragma unroll
        for (int rt = 0; rt < 4; rt++) hb[rt] = *(const bf16x8*)(&buf[rt * 16 + ar][kk + kg * 8]);
        #pragma unroll
        for (int ct = 0; ct < CT; ct++) {
            bf16x8 wf = *(const bf16x8*)(wo + wbase + (long)(c0 + ct * 16 + ar) * D + kk + kg * 8);
            #pragma unroll
            for (int rt = 0; rt < 4; rt++)
                acc[rt][ct] = __builtin_amdgcn_mfma_f32_16x16x32_bf16(wf, hb[rt], acc[rt][ct], 0, 0, 0);
        }
    }

    // ---- epilogue 2: bias + residual (direct from emb), float4 stores ----
    {
        float* ob = out_msgs + (gFA + (long)f0 * A) * 64;
        #pragma unroll
        for (int ct = 0; ct < CT; ct++) {
            const int cb = c0 + ct * 16 + kg * 4;
            const int sres = (c0 + ct * 16) >> 6;      // kg*4 never crosses a segment
            const float4 bo4 = *(const float4*)(bo + g * D + cb);
            #pragma unroll
            for (int rt = 0; rt < 4; rt++) {
                int node = idx_g[fcl[rt] * A + sres];
                bf16x4 xv = *(const bf16x4*)(emb + (long)node * 64 + (cb & 63));
                const int r = rt * 16 + ar;
                float4 o;
                o.x = acc[rt][ct][0] + bo4.x + b2f(xv[0]);
                o.y = acc[rt][ct][1] + bo4.y + b2f(xv[1]);
                o.z = acc[rt][ct][2] + bo4.z + b2f(xv[2]);
                o.w = acc[rt][ct][3] + bo4.w + b2f(xv[3]);
                if (r < valid) *(float4*)(ob + (long)r * D + cb) = o;
            }
        }
    }
}

// ---- R7 fused kernel (fallback when ws too small: f32 on-the-fly path) ----
template<int D, int A, bool PRE, int MINW>
__global__ __launch_bounds__(256, MINW)
void msg_kernel(const void* __restrict__ embv,
                const int* __restrict__ idx,
                const void* __restrict__ wiv, const float* __restrict__ bi,
                const void* __restrict__ wov, const float* __restrict__ bo,
                float* __restrict__ out_msgs, float* __restrict__ out_idx)
{
    constexpr int DP = D + 8;
    constexpr int CT = D / 64;
    constexpr int KS = D / 32;
    constexpr int RC = D / 8;
    __shared__ __hip_bfloat16 buf[TM][DP];

    const int g    = blockIdx.y;
    const int f0   = blockIdx.x * TM;
    const int tid  = threadIdx.x;
    const int lane = tid & 63;
    const int w    = tid >> 6;
    const long gFA = (long)g * NF * A;
    const int valid = min(TM, NF - f0);

    {
        const int* idx_g = idx + gFA + (long)f0 * A;
        #pragma unroll
        for (int c = tid; c < TM * RC; c += 256) {
            int r = c / RC;
            int i = (c - r * RC) * 8;
            bf16x8 v = (bf16x8)0;
            if (r < valid) {
                int node = idx_g[r * A + (i >> 6)];
                if constexpr (PRE) {
                    v = *(const bf16x8*)((const __hip_bfloat16*)embv + (long)node * 64 + (i & 63));
                } else {
                    const float4* s = (const float4*)((const float*)embv + (long)node * 64 + (i & 63));
                    v = cvt8(s[0], s[1]);
                }
            }
            *(bf16x8*)(&buf[r][i]) = v;
        }
        if (tid < valid * A) out_idx[gFA + (long)f0 * A + tid] = (float)idx_g[tid];
    }
    __syncthreads();

    const int ar = lane & 15;
    const int kg = lane >> 4;
    const int c0 = w * (D / 4);
    const long wbase = (long)g * D * D;

    f32x4 acc[4][CT];
    #pragma unroll
    for (int rt = 0; rt < 4; rt++)
        #pragma unroll
        for (int ct = 0; ct < CT; ct++) acc[rt][ct] = (f32x4)0.0f;

    #pragma unroll
    for (int ks = 0; ks < KS; ks++) {
        const int kk = ks * 32;
        bf16x8 xb[4];
        #pragma unroll
        for (int rt = 0; rt < 4; rt++) xb[rt] = *(const bf16x8*)(&buf[rt * 16 + ar][kk + kg * 8]);
        #pragma unroll
        for (int ct = 0; ct < CT; ct++) {
            bf16x8 wf;
            const long wofs = wbase + (long)(c0 + ct * 16 + ar) * D + kk + kg * 8;
            if constexpr (PRE) wf = *(const bf16x8*)((const __hip_bfloat16*)wiv + wofs);
            else { const float4* bp = (const float4*)((const float*)wiv + wofs); wf = cvt8(bp[0], bp[1]); }
            #pragma unroll
            for (int rt = 0; rt < 4; rt++)
                acc[rt][ct] = __builtin_amdgcn_mfma_f32_16x16x32_bf16(wf, xb[rt], acc[rt][ct], 0, 0, 0);
        }
    }

    bf16x4 res[4][CT];
    #pragma unroll
    for (int ct = 0; ct < CT; ct++) {
        const int cb = c0 + ct * 16 + kg * 4;
        #pragma unroll
        for (int rt = 0; rt < 4; rt++)
            res[rt][ct] = *(const bf16x4*)(&buf[rt * 16 + ar][cb]);
    }
    __syncthreads();

    #pragma unroll
    for (int ct = 0; ct < CT; ct++) {
        const int cb = c0 + ct * 16 + kg * 4;
        const float4 bi4 = *(const float4*)(bi + g * D + cb);
        #pragma unroll
        for (int rt = 0; rt < 4; rt++) {
            bf16x4 hv;
            hv[0] = bfs(mish_f(acc[rt][ct][0] + bi4.x));
            hv[1] = bfs(mish_f(acc[rt][ct][1] + bi4.y));
            hv[2] = bfs(mish_f(acc[rt][ct][2] + bi4.z));
            hv[3] = bfs(mish_f(acc[rt][ct][3] + bi4.w));
            *(bf16x4*)(&buf[rt * 16 + ar][cb]) = hv;
        }
    }
    __syncthreads();

    #pragma unroll
    for (int rt = 0; rt < 4; rt++)
        #pragma unroll
        for (int ct = 0; ct < CT; ct++) acc[rt][ct] = (f32x4)0.0f;

    #pragma unroll
    for (int ks = 0; ks < KS; ks++) {
        const int kk = ks * 32;
        bf16x8 hb[4];
        #pragma unroll
        for (int rt = 0; rt < 4; rt++) hb[rt] = *(const bf16x8*)(&buf[rt * 16 + ar][kk + kg * 8]);
        #pragma unroll
        for (int ct = 0; ct < CT; ct++) {
            bf16x8 wf;
            const long wofs = wbase + (long)(c0 + ct * 16 + ar) * D + kk + kg * 8;
            if constexpr (PRE) wf = *(const bf16x8*)((const __hip_bfloat16*)wov + wofs);
            else { const float4* bp = (const float4*)((const float*)wov + wofs); wf = cvt8(bp[0], bp[1]); }
            #pragma unroll
            for (int rt = 0; rt < 4; rt++)
                acc[rt][ct] = __builtin_amdgcn_mfma_f32_16x16x32_bf16(wf, hb[rt], acc[rt][ct], 0, 0, 0);
        }
    }

    {
        float* ob = out_msgs + (gFA + (long)f0 * A) * 64;
        #pragma unroll
        for (int ct = 0; ct < CT; ct++) {
            const int cb = c0 + ct * 16 + kg * 4;
            const float4 bo4 = *(const float4*)(bo + g * D + cb);
            #pragma unroll
            for (int rt = 0; rt < 4; rt++) {
                const int r = rt * 16 + ar;
                float4 o;
                o.x = acc[rt][ct][0] + bo4.x + b2f(res[rt][ct][0]);
                o.y = acc[rt][ct][1] + bo4.y + b2f(res[rt][ct][1]);
                o.z = acc[rt][ct][2] + bo4.z + b2f(res[rt][ct][2]);
                o.w = acc[rt][ct][3] + bo4.w + b2f(res[rt][ct][3]);
                if (r < valid) *(float4*)(ob + (long)r * D + cb) = o;
            }
        }
    }
}

extern "C" void kernel_launch(void* const* d_in, const int* in_sizes, int n_in,
                              void* d_out, int out_size, void* d_ws, size_t ws_size,
                              hipStream_t stream) {
    const float* emb_f = (const float*)d_in[0];
    const int Gs[4] = {2, 3, 2, 1};
    const int Ds[4] = {64, 128, 192, 256};

    const int*   idx_a[4];
    const float *wi_f[4], *bi_f[4], *wo_f[4], *bo_f[4];
    for (int k = 0; k < 4; k++) {
        idx_a[k] = (const int*)d_in[1 + 5 * k];
        wi_f[k]  = (const float*)d_in[2 + 5 * k];
        bi_f[k]  = (const float*)d_in[3 + 5 * k];
        wo_f[k]  = (const float*)d_in[4 + 5 * k];
        bo_f[k]  = (const float*)d_in[5 + 5 * k];
    }

    float* out = (float*)d_out;
    const long MSG_ELEMS = 115200000L;
    const long rowOff[4] = {0, 200000, 800000, 1400000};
    float* om[4]; float* oi[4];
    for (int k = 0; k < 4; k++) {
        om[k] = out + rowOff[k] * 64;
        oi[k] = out + MSG_ELEMS + rowOff[k];
    }

    const long EMB_ELEMS = 6400000L;
    long wPre[9]; wPre[0] = 0;
    for (int k = 0; k < 4; k++) {
        long we = (long)Gs[k] * Ds[k] * Ds[k];
        wPre[2 * k + 1] = wPre[2 * k] + we;
        wPre[2 * k + 2] = wPre[2 * k + 1] + we;
    }
    const long NEED = (EMB_ELEMS + wPre[8]) * 2;

    if (ws_size >= (size_t)NEED) {
        __hip_bfloat16* emb_b = (__hip_bfloat16*)d_ws;
        __hip_bfloat16* w_b   = emb_b + EMB_ELEMS;

        cvt_emb<<<dim3(EMB_ELEMS / 8 / 256), dim3(256), 0, stream>>>(emb_f, emb_b);
        CvtW cw;
        for (int k = 0; k < 4; k++) { cw.src[2 * k] = wi_f[k]; cw.src[2 * k + 1] = wo_f[k]; }
        for (int j = 0; j < 9; j++) cw.pre[j] = wPre[j];
        cvt_w<<<dim3((wPre[8] / 8 + 255) / 256), dim3(256), 0, stream>>>(cw, w_b);

        const __hip_bfloat16 *wi_b[4], *wo_b[4];
        for (int k = 0; k < 4; k++) { wi_b[k] = w_b + wPre[2 * k]; wo_b[k] = w_b + wPre[2 * k + 1]; }

        msg2_kernel<64, 1, 4><<<dim3(NB, 2), 256, 0, stream>>>(
            emb_b, idx_a[0], wi_b[0], bi_f[0], wo_b[0], bo_f[0], om[0], oi[0]);
        msg2_kernel<128, 2, 4><<<dim3(NB, 3), 256, 0, stream>>>(
            emb_b, idx_a[1], wi_b[1], bi_f[1], wo_b[1], bo_f[1], om[1], oi[1]);
        msg2_kernel<192, 3, 3><<<dim3(NB, 2), 256, 0, stream>>>(
            emb_b, idx_a[2], wi_b[2], bi_f[2], wo_b[2], bo_f[2], om[2], oi[2]);
        msg2_kernel<256, 4, 3><<<dim3(NB, 1), 256, 0, stream>>>(
            emb_b, idx_a[3], wi_b[3], bi_f[3], wo_b[3], bo_f[3], om[3], oi[3]);
    } else {
        msg_kernel<64, 1, false, 4><<<dim3(NB, 2), 256, 0, stream>>>(
            emb_f, idx_a[0], wi_f[0], bi_f[0], wo_f[0], bo_f[0], om[0], oi[0]);
        msg_kernel<128, 2, false, 4><<<dim3(NB, 3), 256, 0, stream>>>(
            emb_f, idx_a[1], wi_f[1], bi_f[1], wo_f[1], bo_f[1], om[1], oi[1]);
        msg_kernel<192, 3, false, 4><<<dim3(NB, 2), 256, 0, stream>>>(
            emb_f, idx_a[2], wi_f[2], bi_f[2], wo_f[2], bo_f[2], om[2], oi[2]);
        msg_kernel<256, 4, false, 3><<<dim3(NB, 1), 256, 0, stream>>>(
            emb_f, idx_a[3], wi_f[3], bi_f[3], wo_f[3], bo_f[3], om[3], oi[3]);
    }
}

// Round 11
// 262.956 us; speedup vs baseline: 1.6751x; 1.6751x over previous
//
#include <hip/hip_runtime.h>
#include <hip/hip_bf16.h>

#define NF 100000
#define TM 64
#define NB 1563   // ceil(NF/TM)

typedef __attribute__((ext_vector_type(8))) short bf16x8;
typedef __attribute__((ext_vector_type(4))) short bf16x4;
typedef __attribute__((ext_vector_type(4))) float f32x4;

__device__ __forceinline__ short bfs(float x) {
    union { __hip_bfloat16 h; short s; } u;
    u.h = __float2bfloat16(x);
    return u.s;
}

__device__ __forceinline__ float b2f(short s) {
    union { float f; unsigned u; } u;
    u.u = ((unsigned)(unsigned short)s) << 16;
    return u.f;
}

__device__ __forceinline__ bf16x8 cvt8(const float4 a, const float4 b) {
    bf16x8 r;
    r[0] = bfs(a.x); r[1] = bfs(a.y); r[2] = bfs(a.z); r[3] = bfs(a.w);
    r[4] = bfs(b.x); r[5] = bfs(b.y); r[6] = bfs(b.z); r[7] = bfs(b.w);
    return r;
}

__device__ __forceinline__ float mish_f(float v) {
    float t = __expf(v);
    float p = t * (t + 2.0f);
    float r = v * p * __builtin_amdgcn_rcpf(p + 2.0f);
    return (v > 20.0f) ? v : r;
}

// ---- fp32 -> bf16 pre-conversion ----
__global__ __launch_bounds__(256)
void cvt_emb(const float* __restrict__ in, __hip_bfloat16* __restrict__ out) {
    long e = ((long)blockIdx.x * 256 + threadIdx.x) * 8;
    const float4* s = (const float4*)(in + e);
    *(bf16x8*)(out + e) = cvt8(s[0], s[1]);
}

// Weight repack: row-major [g][n][k] f32 -> K-slab bf16 [g][k/32][n][32].
// A wave's wf fragment (lane=(ar,kg), slab ks) then reads 1KB CONTIGUOUS:
// off = g*D*D + ks*32*D + n*32 + (k%32).
struct CvtW {
    const float* src[8];
    long pre[9];
    int  Dv[8];
};

__global__ __launch_bounds__(256)
void cvt_w(CvtW a, __hip_bfloat16* __restrict__ dst) {
    long e = ((long)blockIdx.x * 256 + threadIdx.x) * 8;
    if (e >= a.pre[8]) return;
    int j = 0;
    #pragma unroll
    for (int q = 0; q < 8; q++) if (e >= a.pre[q + 1]) j = q + 1;
    long le = e - a.pre[j];
    const int D = a.Dv[j];
    int g = (int)(le / ((long)D * D));
    int rem = (int)(le - (long)g * D * D);
    int n = rem / D;
    int k = rem - n * D;                       // multiple of 8, stays within a 32-slab
    const float4* s = (const float4*)(a.src[j] + le);
    long off = a.pre[j] + (long)g * D * D + (long)(k >> 5) * 32 * D + n * 32 + (k & 31);
    *(bf16x8*)(dst + off) = cvt8(s[0], s[1]);
}

// ---- per-group fused kernel (R7 structure + MLP upgrades) ----
// 4 waves, each: all 64 facts x D/4 cols (RT=4, CT=D/64). Swapped MFMA
// (A=weight frag, B=fact frag) -> 4 consecutive out cols/lane. Single LDS
// buffer (X then H), residual snapshotted to VGPRs. Weights in K-slab layout
// (coalesced 1KB wf loads). Wi slab-0 pre-issued before the gather barrier,
// Wo slab-0 pre-issued before the mish epilogue + barrier.
template<int D, int A, int MINW>
__global__ __launch_bounds__(256, MINW)
void msg3_kernel(const __hip_bfloat16* __restrict__ emb,
                 const int* __restrict__ idx,
                 const __hip_bfloat16* __restrict__ wi, const float* __restrict__ bi,
                 const __hip_bfloat16* __restrict__ wo, const float* __restrict__ bo,
                 float* __restrict__ out_msgs, float* __restrict__ out_idx)
{
    constexpr int DP = D + 8;
    constexpr int CT = D / 64;
    constexpr int KS = D / 32;
    constexpr int RC = D / 8;
    constexpr int CH = (TM * RC) / 256;        // 16B gather chunks per thread
    __shared__ __hip_bfloat16 buf[TM][DP];

    const int g    = blockIdx.y;
    const int f0   = blockIdx.x * TM;
    const int tid  = threadIdx.x;
    const int lane = tid & 63;
    const int w    = tid >> 6;
    const long gFA = (long)g * NF * A;
    const int valid = min(TM, NF - f0);
    const int* idx_g = idx + gFA + (long)f0 * A;

    const int ar = lane & 15;
    const int kg = lane >> 4;
    const int c0 = w * (D / 4);
    // K-slab weight base for this lane: g*D*D + n*32 + kg*8, advance 32*D per slab
    const long wlane = (long)g * D * D + (long)(c0 + ar) * 32 + kg * 8;

    // ---- gather with explicit MLP: all idx loads, then all emb loads ----
    {
        int nodes[CH];
        #pragma unroll
        for (int j = 0; j < CH; j++) {
            int c = tid + j * 256;
            int r = c / RC;
            nodes[j] = (r < valid) ? idx_g[r * A + ((c % RC) >> 3)] : idx_g[0];
        }
        bf16x8 v[CH];
        #pragma unroll
        for (int j = 0; j < CH; j++) {
            int c = tid + j * 256;
            int i = (c % RC) * 8;
            v[j] = *(const bf16x8*)(emb + (long)nodes[j] * 64 + (i & 63));
        }
        #pragma unroll
        for (int j = 0; j < CH; j++) {
            int c = tid + j * 256;
            *(bf16x8*)(&buf[c / RC][(c % RC) * 8]) = v[j];
        }
        if (tid < valid * A) out_idx[gFA + (long)f0 * A + tid] = (float)idx_g[tid];
    }

    // pre-issue Wi slab 0 (independent of LDS; retires across the barrier)
    bf16x8 wi0[CT];
    #pragma unroll
    for (int ct = 0; ct < CT; ct++)
        wi0[ct] = *(const bf16x8*)(wi + wlane + ct * 16 * 32);

    __syncthreads();

    f32x4 acc[4][CT];
    #pragma unroll
    for (int rt = 0; rt < 4; rt++)
        #pragma unroll
        for (int ct = 0; ct < CT; ct++) acc[rt][ct] = (f32x4)0.0f;

    // ---- GEMM1: Wi x X^T (K-slab weight walk) ----
    #pragma unroll
    for (int ks = 0; ks < KS; ks++) {
        const int kk = ks * 32;
        bf16x8 xb[4];
        #pragma unroll
        for (int rt = 0; rt < 4; rt++) xb[rt] = *(const bf16x8*)(&buf[rt * 16 + ar][kk + kg * 8]);
        #pragma unroll
        for (int ct = 0; ct < CT; ct++) {
            bf16x8 wf = (ks == 0) ? wi0[ct]
                      : *(const bf16x8*)(wi + wlane + (long)ks * 32 * D + ct * 16 * 32);
            #pragma unroll
            for (int rt = 0; rt < 4; rt++)
                acc[rt][ct] = __builtin_amdgcn_mfma_f32_16x16x32_bf16(wf, xb[rt], acc[rt][ct], 0, 0, 0);
        }
    }

    // ---- snapshot residual X values ----
    bf16x4 res[4][CT];
    #pragma unroll
    for (int ct = 0; ct < CT; ct++) {
        const int cb = c0 + ct * 16 + kg * 4;
        #pragma unroll
        for (int rt = 0; rt < 4; rt++)
            res[rt][ct] = *(const bf16x4*)(&buf[rt * 16 + ar][cb]);
    }

    // pre-issue Wo slab 0 (hides under mish epilogue + barrier)
    bf16x8 wo0[CT];
    #pragma unroll
    for (int ct = 0; ct < CT; ct++)
        wo0[ct] = *(const bf16x8*)(wo + wlane + ct * 16 * 32);

    __syncthreads();   // all X reads complete before H overwrites buf

    // ---- epilogue 1: bias + mish -> buf (H) ----
    #pragma unroll
    for (int ct = 0; ct < CT; ct++) {
        const int cb = c0 + ct * 16 + kg * 4;
        const float4 bi4 = *(const float4*)(bi + g * D + cb);
        #pragma unroll
        for (int rt = 0; rt < 4; rt++) {
            bf16x4 hv;
            hv[0] = bfs(mish_f(acc[rt][ct][0] + bi4.x));
            hv[1] = bfs(mish_f(acc[rt][ct][1] + bi4.y));
            hv[2] = bfs(mish_f(acc[rt][ct][2] + bi4.z));
            hv[3] = bfs(mish_f(acc[rt][ct][3] + bi4.w));
            *(bf16x4*)(&buf[rt * 16 + ar][cb]) = hv;
        }
    }
    __syncthreads();

    // ---- GEMM2: Wo x H^T ----
    #pragma unroll
    for (int rt = 0; rt < 4; rt++)
        #pragma unroll
        for (int ct = 0; ct < CT; ct++) acc[rt][ct] = (f32x4)0.0f;

    #pragma unroll
    for (int ks = 0; ks < KS; ks++) {
        const int kk = ks * 32;
        bf16x8 hb[4];
        #pragma unroll
        for (int rt = 0; rt < 4; rt++) hb[rt] = *(const bf16x8*)(&buf[rt * 16 + ar][kk + kg * 8]);
        #pragma unroll
        for (int ct = 0; ct < CT; ct++) {
            bf16x8 wf = (ks == 0) ? wo0[ct]
                      : *(const bf16x8*)(wo + wlane + (long)ks * 32 * D + ct * 16 * 32);
            #pragma unroll
            for (int rt = 0; rt < 4; rt++)
                acc[rt][ct] = __builtin_amdgcn_mfma_f32_16x16x32_bf16(wf, hb[rt], acc[rt][ct], 0, 0, 0);
        }
    }

    // ---- epilogue 2: bias + residual(regs), float4 stores ----
    {
        float* ob = out_msgs + (gFA + (long)f0 * A) * 64;
        #pragma unroll
        for (int ct = 0; ct < CT; ct++) {
            const int cb = c0 + ct * 16 + kg * 4;
            const float4 bo4 = *(const float4*)(bo + g * D + cb);
            #pragma unroll
            for (int rt = 0; rt < 4; rt++) {
                const int r = rt * 16 + ar;
                float4 o;
                o.x = acc[rt][ct][0] + bo4.x + b2f(res[rt][ct][0]);
                o.y = acc[rt][ct][1] + bo4.y + b2f(res[rt][ct][1]);
                o.z = acc[rt][ct][2] + bo4.z + b2f(res[rt][ct][2]);
                o.w = acc[rt][ct][3] + bo4.w + b2f(res[rt][ct][3]);
                if (r < valid) *(float4*)(ob + (long)r * D + cb) = o;
            }
        }
    }
}

// ---- fallback (ws too small): R7 on-the-fly f32 path, row-major weights ----
template<int D, int A, int MINW>
__global__ __launch_bounds__(256, MINW)
void msg_kernel(const float* __restrict__ embv,
                const int* __restrict__ idx,
                const float* __restrict__ wiv, const float* __restrict__ bi,
                const float* __restrict__ wov, const float* __restrict__ bo,
                float* __restrict__ out_msgs, float* __restrict__ out_idx)
{
    constexpr int DP = D + 8;
    constexpr int CT = D / 64;
    constexpr int KS = D / 32;
    constexpr int RC = D / 8;
    __shared__ __hip_bfloat16 buf[TM][DP];

    const int g    = blockIdx.y;
    const int f0   = blockIdx.x * TM;
    const int tid  = threadIdx.x;
    const int lane = tid & 63;
    const int w    = tid >> 6;
    const long gFA = (long)g * NF * A;
    const int valid = min(TM, NF - f0);

    {
        const int* idx_g = idx + gFA + (long)f0 * A;
        #pragma unroll
        for (int c = tid; c < TM * RC; c += 256) {
            int r = c / RC;
            int i = (c - r * RC) * 8;
            bf16x8 v = (bf16x8)0;
            if (r < valid) {
                int node = idx_g[r * A + (i >> 6)];
                const float4* s = (const float4*)(embv + (long)node * 64 + (i & 63));
                v = cvt8(s[0], s[1]);
            }
            *(bf16x8*)(&buf[r][i]) = v;
        }
        if (tid < valid * A) out_idx[gFA + (long)f0 * A + tid] = (float)idx_g[tid];
    }
    __syncthreads();

    const int ar = lane & 15;
    const int kg = lane >> 4;
    const int c0 = w * (D / 4);
    const long wbase = (long)g * D * D;

    f32x4 acc[4][CT];
    #pragma unroll
    for (int rt = 0; rt < 4; rt++)
        #pragma unroll
        for (int ct = 0; ct < CT; ct++) acc[rt][ct] = (f32x4)0.0f;

    #pragma unroll
    for (int ks = 0; ks < KS; ks++) {
        const int kk = ks * 32;
        bf16x8 xb[4];
        #pragma unroll
        for (int rt = 0; rt < 4; rt++) xb[rt] = *(const bf16x8*)(&buf[rt * 16 + ar][kk + kg * 8]);
        #pragma unroll
        for (int ct = 0; ct < CT; ct++) {
            const float4* bp = (const float4*)(wiv + wbase + (long)(c0 + ct * 16 + ar) * D + kk + kg * 8);
            bf16x8 wf = cvt8(bp[0], bp[1]);
            #pragma unroll
            for (int rt = 0; rt < 4; rt++)
                acc[rt][ct] = __builtin_amdgcn_mfma_f32_16x16x32_bf16(wf, xb[rt], acc[rt][ct], 0, 0, 0);
        }
    }

    bf16x4 res[4][CT];
    #pragma unroll
    for (int ct = 0; ct < CT; ct++) {
        const int cb = c0 + ct * 16 + kg * 4;
        #pragma unroll
        for (int rt = 0; rt < 4; rt++)
            res[rt][ct] = *(const bf16x4*)(&buf[rt * 16 + ar][cb]);
    }
    __syncthreads();

    #pragma unroll
    for (int ct = 0; ct < CT; ct++) {
        const int cb = c0 + ct * 16 + kg * 4;
        const float4 bi4 = *(const float4*)(bi + g * D + cb);
        #pragma unroll
        for (int rt = 0; rt < 4; rt++) {
            bf16x4 hv;
            hv[0] = bfs(mish_f(acc[rt][ct][0] + bi4.x));
            hv[1] = bfs(mish_f(acc[rt][ct][1] + bi4.y));
            hv[2] = bfs(mish_f(acc[rt][ct][2] + bi4.z));
            hv[3] = bfs(mish_f(acc[rt][ct][3] + bi4.w));
            *(bf16x4*)(&buf[rt * 16 + ar][cb]) = hv;
        }
    }
    __syncthreads();

    #pragma unroll
    for (int rt = 0; rt < 4; rt++)
        #pragma unroll
        for (int ct = 0; ct < CT; ct++) acc[rt][ct] = (f32x4)0.0f;

    #pragma unroll
    for (int ks = 0; ks < KS; ks++) {
        const int kk = ks * 32;
        bf16x8 hb[4];
        #pragma unroll
        for (int rt = 0; rt < 4; rt++) hb[rt] = *(const bf16x8*)(&buf[rt * 16 + ar][kk + kg * 8]);
        #pragma unroll
        for (int ct = 0; ct < CT; ct++) {
            const float4* bp = (const float4*)(wov + wbase + (long)(c0 + ct * 16 + ar) * D + kk + kg * 8);
            bf16x8 wf = cvt8(bp[0], bp[1]);
            #pragma unroll
            for (int rt = 0; rt < 4; rt++)
                acc[rt][ct] = __builtin_amdgcn_mfma_f32_16x16x32_bf16(wf, hb[rt], acc[rt][ct], 0, 0, 0);
        }
    }

    {
        float* ob = out_msgs + (gFA + (long)f0 * A) * 64;
        #pragma unroll
        for (int ct = 0; ct < CT; ct++) {
            const int cb = c0 + ct * 16 + kg * 4;
            const float4 bo4 = *(const float4*)(bo + g * D + cb);
            #pragma unroll
            for (int rt = 0; rt < 4; rt++) {
                const int r = rt * 16 + ar;
                float4 o;
                o.x = acc[rt][ct][0] + bo4.x + b2f(res[rt][ct][0]);
                o.y = acc[rt][ct][1] + bo4.y + b2f(res[rt][ct][1]);
                o.z = acc[rt][ct][2] + bo4.z + b2f(res[rt][ct][2]);
                o.w = acc[rt][ct][3] + bo4.w + b2f(res[rt][ct][3]);
                if (r < valid) *(float4*)(ob + (long)r * D + cb) = o;
            }
        }
    }
}

extern "C" void kernel_launch(void* const* d_in, const int* in_sizes, int n_in,
                              void* d_out, int out_size, void* d_ws, size_t ws_size,
                              hipStream_t stream) {
    const float* emb_f = (const float*)d_in[0];
    const int Gs[4] = {2, 3, 2, 1};
    const int Ds[4] = {64, 128, 192, 256};

    const int*   idx_a[4];
    const float *wi_f[4], *bi_f[4], *wo_f[4], *bo_f[4];
    for (int k = 0; k < 4; k++) {
        idx_a[k] = (const int*)d_in[1 + 5 * k];
        wi_f[k]  = (const float*)d_in[2 + 5 * k];
        bi_f[k]  = (const float*)d_in[3 + 5 * k];
        wo_f[k]  = (const float*)d_in[4 + 5 * k];
        bo_f[k]  = (const float*)d_in[5 + 5 * k];
    }

    float* out = (float*)d_out;
    const long MSG_ELEMS = 115200000L;
    const long rowOff[4] = {0, 200000, 800000, 1400000};
    float* om[4]; float* oi[4];
    for (int k = 0; k < 4; k++) {
        om[k] = out + rowOff[k] * 64;
        oi[k] = out + MSG_ELEMS + rowOff[k];
    }

    const long EMB_ELEMS = 6400000L;
    long wPre[9]; wPre[0] = 0;
    int  wD[8];
    for (int k = 0; k < 4; k++) {
        long we = (long)Gs[k] * Ds[k] * Ds[k];
        wPre[2 * k + 1] = wPre[2 * k] + we;
        wPre[2 * k + 2] = wPre[2 * k + 1] + we;
        wD[2 * k] = Ds[k]; wD[2 * k + 1] = Ds[k];
    }
    const long NEED = (EMB_ELEMS + wPre[8]) * 2;

    if (ws_size >= (size_t)NEED) {
        __hip_bfloat16* emb_b = (__hip_bfloat16*)d_ws;
        __hip_bfloat16* w_b   = emb_b + EMB_ELEMS;

        cvt_emb<<<dim3(EMB_ELEMS / 8 / 256), dim3(256), 0, stream>>>(emb_f, emb_b);
        CvtW cw;
        for (int k = 0; k < 4; k++) { cw.src[2 * k] = wi_f[k]; cw.src[2 * k + 1] = wo_f[k]; }
        for (int j = 0; j < 9; j++) cw.pre[j] = wPre[j];
        for (int j = 0; j < 8; j++) cw.Dv[j] = wD[j];
        cvt_w<<<dim3((wPre[8] / 8 + 255) / 256), dim3(256), 0, stream>>>(cw, w_b);

        const __hip_bfloat16 *wi_b[4], *wo_b[4];
        for (int k = 0; k < 4; k++) { wi_b[k] = w_b + wPre[2 * k]; wo_b[k] = w_b + wPre[2 * k + 1]; }

        msg3_kernel<64, 1, 4><<<dim3(NB, 2), 256, 0, stream>>>(
            emb_b, idx_a[0], wi_b[0], bi_f[0], wo_b[0], bo_f[0], om[0], oi[0]);
        msg3_kernel<128, 2, 4><<<dim3(NB, 3), 256, 0, stream>>>(
            emb_b, idx_a[1], wi_b[1], bi_f[1], wo_b[1], bo_f[1], om[1], oi[1]);
        msg3_kernel<192, 3, 3><<<dim3(NB, 2), 256, 0, stream>>>(
            emb_b, idx_a[2], wi_b[2], bi_f[2], wo_b[2], bo_f[2], om[2], oi[2]);
        msg3_kernel<256, 4, 3><<<dim3(NB, 1), 256, 0, stream>>>(
            emb_b, idx_a[3], wi_b[3], bi_f[3], wo_b[3], bo_f[3], om[3], oi[3]);
    } else {
        msg_kernel<64, 1, 4><<<dim3(NB, 2), 256, 0, stream>>>(
            emb_f, idx_a[0], wi_f[0], bi_f[0], wo_f[0], bo_f[0], om[0], oi[0]);
        msg_kernel<128, 2, 4><<<dim3(NB, 3), 256, 0, stream>>>(
            emb_f, idx_a[1], wi_f[1], bi_f[1], wo_f[1], bo_f[1], om[1], oi[1]);
        msg_kernel<192, 3, 4><<<dim3(NB, 2), 256, 0, stream>>>(
            emb_f, idx_a[2], wi_f[2], bi_f[2], wo_f[2], bo_f[2], om[2], oi[2]);
        msg_kernel<256, 4, 3><<<dim3(NB, 1), 256, 0, stream>>>(
            emb_f, idx_a[3], wi_f[3], bi_f[3], wo_f[3], bo_f[3], om[3], oi[3]);
    }
}

// Round 12
// 207.309 us; speedup vs baseline: 2.1247x; 1.2684x over previous
//
#include <hip/hip_runtime.h>
#include <hip/hip_bf16.h>

#define NF 100000
#define TM 64
#define NB 1563   // ceil(NF/TM)

typedef __attribute__((ext_vector_type(8))) short bf16x8;
typedef __attribute__((ext_vector_type(4))) short bf16x4;
typedef __attribute__((ext_vector_type(4))) float f32x4;

__device__ __forceinline__ short bfs(float x) {
    union { __hip_bfloat16 h; short s; } u;
    u.h = __float2bfloat16(x);
    return u.s;
}

__device__ __forceinline__ float b2f(short s) {
    union { float f; unsigned u; } u;
    u.u = ((unsigned)(unsigned short)s) << 16;
    return u.f;
}

__device__ __forceinline__ bf16x8 cvt8(const float4 a, const float4 b) {
    bf16x8 r;
    r[0] = bfs(a.x); r[1] = bfs(a.y); r[2] = bfs(a.z); r[3] = bfs(a.w);
    r[4] = bfs(b.x); r[5] = bfs(b.y); r[6] = bfs(b.z); r[7] = bfs(b.w);
    return r;
}

__device__ __forceinline__ float mish_f(float v) {
    float t = __expf(v);
    float p = t * (t + 2.0f);
    float r = v * p * __builtin_amdgcn_rcpf(p + 2.0f);
    return (v > 20.0f) ? v : r;
}

// ---- merged fp32->bf16 conversion: embeddings (linear) + weights (K-slab) ----
// Weight repack: row-major [g][n][k] f32 -> K-slab bf16 [g][k/32][n][32]; a wave's
// wf fragment (lane=(ar,kg), slab ks) then reads 1KB contiguous.
struct CvtA {
    const float* src[8];
    long pre[9];
    int  Dv[8];
    const float* emb;
    long embElems;
};

__global__ __launch_bounds__(256)
void cvt_all(CvtA a, __hip_bfloat16* __restrict__ dst) {
    long e = ((long)blockIdx.x * 256 + threadIdx.x) * 8;
    if (e < a.embElems) {
        const float4* s = (const float4*)(a.emb + e);
        *(bf16x8*)(dst + e) = cvt8(s[0], s[1]);
        return;
    }
    long we = e - a.embElems;
    if (we >= a.pre[8]) return;
    int j = 0;
    #pragma unroll
    for (int q = 0; q < 8; q++) if (we >= a.pre[q + 1]) j = q + 1;
    long le = we - a.pre[j];
    const int D = a.Dv[j];
    int g = (int)(le / ((long)D * D));
    int rem = (int)(le - (long)g * D * D);
    int n = rem / D;
    int k = rem - n * D;                       // multiple of 8, within one 32-slab
    const float4* s = (const float4*)(a.src[j] + le);
    long off = a.embElems + a.pre[j] + (long)g * D * D + (long)(k >> 5) * 32 * D + n * 32 + (k & 31);
    *(bf16x8*)(dst + off) = cvt8(s[0], s[1]);
}

// ---- per-group fused kernel (R11 + weight-in-regs + nontemporal stores) ----
// 4 waves, each: all 64 facts x D/4 cols (RT=4, CT=D/64). Swapped MFMA
// (A=weight frag, B=fact frag) -> 4 consecutive out cols/lane. Single LDS
// buffer (X then H), residual snapshotted to VGPRs. K-slab weights:
//   D<=128: ALL Wi frags preloaded before the gather barrier, ALL Wo frags
//           right after GEMM1 (latency hidden under barrier/mish).
//   D>=192: 1-slab-ahead double-buffered prefetch (wcur/wnx).
template<int D, int A, int MINW>
__global__ __launch_bounds__(256, MINW)
void msg3_kernel(const __hip_bfloat16* __restrict__ emb,
                 const int* __restrict__ idx,
                 const __hip_bfloat16* __restrict__ wi, const float* __restrict__ bi,
                 const __hip_bfloat16* __restrict__ wo, const float* __restrict__ bo,
                 float* __restrict__ out_msgs, float* __restrict__ out_idx)
{
    constexpr int DP = D + 8;
    constexpr int CT = D / 64;
    constexpr int KS = D / 32;
    constexpr int RC = D / 8;
    constexpr int CH = (TM * RC) / 256;
    constexpr bool FULLW = (D <= 128);
    __shared__ __hip_bfloat16 buf[TM][DP];

    const int g    = blockIdx.y;
    const int f0   = blockIdx.x * TM;
    const int tid  = threadIdx.x;
    const int lane = tid & 63;
    const int w    = tid >> 6;
    const long gFA = (long)g * NF * A;
    const int valid = min(TM, NF - f0);
    const int* idx_g = idx + gFA + (long)f0 * A;

    const int ar = lane & 15;
    const int kg = lane >> 4;
    const int c0 = w * (D / 4);
    const long wlane = (long)g * D * D + (long)(c0 + ar) * 32 + kg * 8;

    // ---- gather with explicit MLP ----
    {
        int nodes[CH];
        #pragma unroll
        for (int j = 0; j < CH; j++) {
            int c = tid + j * 256;
            int r = c / RC;
            nodes[j] = (r < valid) ? idx_g[r * A + ((c % RC) >> 3)] : idx_g[0];
        }
        bf16x8 v[CH];
        #pragma unroll
        for (int j = 0; j < CH; j++) {
            int c = tid + j * 256;
            v[j] = *(const bf16x8*)(emb + (long)nodes[j] * 64 + (((c % RC) * 8) & 63));
        }
        #pragma unroll
        for (int j = 0; j < CH; j++) {
            int c = tid + j * 256;
            *(bf16x8*)(&buf[c / RC][(c % RC) * 8]) = v[j];
        }
        if (tid < valid * A)
            __builtin_nontemporal_store((float)idx_g[tid], &out_idx[gFA + (long)f0 * A + tid]);
    }

    f32x4 acc[4][CT];
    #pragma unroll
    for (int rt = 0; rt < 4; rt++)
        #pragma unroll
        for (int ct = 0; ct < CT; ct++) acc[rt][ct] = (f32x4)0.0f;

    if constexpr (FULLW) {
        // ---- preload ALL Wi frags (retire across the barrier) ----
        bf16x8 wia[KS][CT];
        #pragma unroll
        for (int ks = 0; ks < KS; ks++)
            #pragma unroll
            for (int ct = 0; ct < CT; ct++)
                wia[ks][ct] = *(const bf16x8*)(wi + wlane + (long)ks * 32 * D + ct * 512);

        __syncthreads();

        // ---- GEMM1: zero in-loop global loads ----
        #pragma unroll
        for (int ks = 0; ks < KS; ks++) {
            const int kk = ks * 32;
            bf16x8 xb[4];
            #pragma unroll
            for (int rt = 0; rt < 4; rt++) xb[rt] = *(const bf16x8*)(&buf[rt * 16 + ar][kk + kg * 8]);
            #pragma unroll
            for (int ct = 0; ct < CT; ct++)
                #pragma unroll
                for (int rt = 0; rt < 4; rt++)
                    acc[rt][ct] = __builtin_amdgcn_mfma_f32_16x16x32_bf16(wia[ks][ct], xb[rt], acc[rt][ct], 0, 0, 0);
        }

        // ---- preload ALL Wo frags (hide under res + barrier + mish) ----
        bf16x8 woa[KS][CT];
        #pragma unroll
        for (int ks = 0; ks < KS; ks++)
            #pragma unroll
            for (int ct = 0; ct < CT; ct++)
                woa[ks][ct] = *(const bf16x8*)(wo + wlane + (long)ks * 32 * D + ct * 512);

        bf16x4 res[4][CT];
        #pragma unroll
        for (int ct = 0; ct < CT; ct++) {
            const int cb = c0 + ct * 16 + kg * 4;
            #pragma unroll
            for (int rt = 0; rt < 4; rt++)
                res[rt][ct] = *(const bf16x4*)(&buf[rt * 16 + ar][cb]);
        }
        __syncthreads();

        #pragma unroll
        for (int ct = 0; ct < CT; ct++) {
            const int cb = c0 + ct * 16 + kg * 4;
            const float4 bi4 = *(const float4*)(bi + g * D + cb);
            #pragma unroll
            for (int rt = 0; rt < 4; rt++) {
                bf16x4 hv;
                hv[0] = bfs(mish_f(acc[rt][ct][0] + bi4.x));
                hv[1] = bfs(mish_f(acc[rt][ct][1] + bi4.y));
                hv[2] = bfs(mish_f(acc[rt][ct][2] + bi4.z));
                hv[3] = bfs(mish_f(acc[rt][ct][3] + bi4.w));
                *(bf16x4*)(&buf[rt * 16 + ar][cb]) = hv;
            }
        }
        __syncthreads();

        #pragma unroll
        for (int rt = 0; rt < 4; rt++)
            #pragma unroll
            for (int ct = 0; ct < CT; ct++) acc[rt][ct] = (f32x4)0.0f;

        #pragma unroll
        for (int ks = 0; ks < KS; ks++) {
            const int kk = ks * 32;
            bf16x8 hb[4];
            #pragma unroll
            for (int rt = 0; rt < 4; rt++) hb[rt] = *(const bf16x8*)(&buf[rt * 16 + ar][kk + kg * 8]);
            #pragma unroll
            for (int ct = 0; ct < CT; ct++)
                #pragma unroll
                for (int rt = 0; rt < 4; rt++)
                    acc[rt][ct] = __builtin_amdgcn_mfma_f32_16x16x32_bf16(woa[ks][ct], hb[rt], acc[rt][ct], 0, 0, 0);
        }

        float* ob = out_msgs + (gFA + (long)f0 * A) * 64;
        #pragma unroll
        for (int ct = 0; ct < CT; ct++) {
            const int cb = c0 + ct * 16 + kg * 4;
            const float4 bo4 = *(const float4*)(bo + g * D + cb);
            #pragma unroll
            for (int rt = 0; rt < 4; rt++) {
                const int r = rt * 16 + ar;
                f32x4 o;
                o[0] = acc[rt][ct][0] + bo4.x + b2f(res[rt][ct][0]);
                o[1] = acc[rt][ct][1] + bo4.y + b2f(res[rt][ct][1]);
                o[2] = acc[rt][ct][2] + bo4.z + b2f(res[rt][ct][2]);
                o[3] = acc[rt][ct][3] + bo4.w + b2f(res[rt][ct][3]);
                if (r < valid)
                    __builtin_nontemporal_store(o, (f32x4*)(ob + (long)r * D + cb));
            }
        }
    } else {
        // ---- D>=192: 1-slab-ahead double-buffered weight prefetch ----
        bf16x8 wcur[CT];
        #pragma unroll
        for (int ct = 0; ct < CT; ct++)
            wcur[ct] = *(const bf16x8*)(wi + wlane + ct * 512);

        __syncthreads();

        #pragma unroll
        for (int ks = 0; ks < KS; ks++) {
            bf16x8 wnx[CT];
            if (ks + 1 < KS)
                #pragma unroll
                for (int ct = 0; ct < CT; ct++)
                    wnx[ct] = *(const bf16x8*)(wi + wlane + (long)(ks + 1) * 32 * D + ct * 512);
            const int kk = ks * 32;
            bf16x8 xb[4];
            #pragma unroll
            for (int rt = 0; rt < 4; rt++) xb[rt] = *(const bf16x8*)(&buf[rt * 16 + ar][kk + kg * 8]);
            #pragma unroll
            for (int ct = 0; ct < CT; ct++)
                #pragma unroll
                for (int rt = 0; rt < 4; rt++)
                    acc[rt][ct] = __builtin_amdgcn_mfma_f32_16x16x32_bf16(wcur[ct], xb[rt], acc[rt][ct], 0, 0, 0);
            if (ks + 1 < KS)
                #pragma unroll
                for (int ct = 0; ct < CT; ct++) wcur[ct] = wnx[ct];
        }

        // pre-issue Wo slab 0 (hides under res + barrier + mish)
        #pragma unroll
        for (int ct = 0; ct < CT; ct++)
            wcur[ct] = *(const bf16x8*)(wo + wlane + ct * 512);

        bf16x4 res[4][CT];
        #pragma unroll
        for (int ct = 0; ct < CT; ct++) {
            const int cb = c0 + ct * 16 + kg * 4;
            #pragma unroll
            for (int rt = 0; rt < 4; rt++)
                res[rt][ct] = *(const bf16x4*)(&buf[rt * 16 + ar][cb]);
        }
        __syncthreads();

        #pragma unroll
        for (int ct = 0; ct < CT; ct++) {
            const int cb = c0 + ct * 16 + kg * 4;
            const float4 bi4 = *(const float4*)(bi + g * D + cb);
            #pragma unroll
            for (int rt = 0; rt < 4; rt++) {
                bf16x4 hv;
                hv[0] = bfs(mish_f(acc[rt][ct][0] + bi4.x));
                hv[1] = bfs(mish_f(acc[rt][ct][1] + bi4.y));
                hv[2] = bfs(mish_f(acc[rt][ct][2] + bi4.z));
                hv[3] = bfs(mish_f(acc[rt][ct][3] + bi4.w));
                *(bf16x4*)(&buf[rt * 16 + ar][cb]) = hv;
            }
        }
        __syncthreads();

        #pragma unroll
        for (int rt = 0; rt < 4; rt++)
            #pragma unroll
            for (int ct = 0; ct < CT; ct++) acc[rt][ct] = (f32x4)0.0f;

        #pragma unroll
        for (int ks = 0; ks < KS; ks++) {
            bf16x8 wnx[CT];
            if (ks + 1 < KS)
                #pragma unroll
                for (int ct = 0; ct < CT; ct++)
                    wnx[ct] = *(const bf16x8*)(wo + wlane + (long)(ks + 1) * 32 * D + ct * 512);
            const int kk = ks * 32;
            bf16x8 hb[4];
            #pragma unroll
            for (int rt = 0; rt < 4; rt++) hb[rt] = *(const bf16x8*)(&buf[rt * 16 + ar][kk + kg * 8]);
            #pragma unroll
            for (int ct = 0; ct < CT; ct++)
                #pragma unroll
                for (int rt = 0; rt < 4; rt++)
                    acc[rt][ct] = __builtin_amdgcn_mfma_f32_16x16x32_bf16(wcur[ct], hb[rt], acc[rt][ct], 0, 0, 0);
            if (ks + 1 < KS)
                #pragma unroll
                for (int ct = 0; ct < CT; ct++) wcur[ct] = wnx[ct];
        }

        float* ob = out_msgs + (gFA + (long)f0 * A) * 64;
        #pragma unroll
        for (int ct = 0; ct < CT; ct++) {
            const int cb = c0 + ct * 16 + kg * 4;
            const float4 bo4 = *(const float4*)(bo + g * D + cb);
            #pragma unroll
            for (int rt = 0; rt < 4; rt++) {
                const int r = rt * 16 + ar;
                f32x4 o;
                o[0] = acc[rt][ct][0] + bo4.x + b2f(res[rt][ct][0]);
                o[1] = acc[rt][ct][1] + bo4.y + b2f(res[rt][ct][1]);
                o[2] = acc[rt][ct][2] + bo4.z + b2f(res[rt][ct][2]);
                o[3] = acc[rt][ct][3] + bo4.w + b2f(res[rt][ct][3]);
                if (r < valid)
                    __builtin_nontemporal_store(o, (f32x4*)(ob + (long)r * D + cb));
            }
        }
    }
}

// ---- fallback (ws too small): R11 on-the-fly f32 path, row-major weights ----
template<int D, int A, int MINW>
__global__ __launch_bounds__(256, MINW)
void msg_kernel(const float* __restrict__ embv,
                const int* __restrict__ idx,
                const float* __restrict__ wiv, const float* __restrict__ bi,
                const float* __restrict__ wov, const float* __restrict__ bo,
                float* __restrict__ out_msgs, float* __restrict__ out_idx)
{
    constexpr int DP = D + 8;
    constexpr int CT = D / 64;
    constexpr int KS = D / 32;
    constexpr int RC = D / 8;
    __shared__ __hip_bfloat16 buf[TM][DP];

    const int g    = blockIdx.y;
    const int f0   = blockIdx.x * TM;
    const int tid  = threadIdx.x;
    const int lane = tid & 63;
    const int w    = tid >> 6;
    const long gFA = (long)g * NF * A;
    const int valid = min(TM, NF - f0);

    {
        const int* idx_g = idx + gFA + (long)f0 * A;
        #pragma unroll
        for (int c = tid; c < TM * RC; c += 256) {
            int r = c / RC;
            int i = (c - r * RC) * 8;
            bf16x8 v = (bf16x8)0;
            if (r < valid) {
                int node = idx_g[r * A + (i >> 6)];
                const float4* s = (const float4*)(embv + (long)node * 64 + (i & 63));
                v = cvt8(s[0], s[1]);
            }
            *(bf16x8*)(&buf[r][i]) = v;
        }
        if (tid < valid * A) out_idx[gFA + (long)f0 * A + tid] = (float)idx_g[tid];
    }
    __syncthreads();

    const int ar = lane & 15;
    const int kg = lane >> 4;
    const int c0 = w * (D / 4);
    const long wbase = (long)g * D * D;

    f32x4 acc[4][CT];
    #pragma unroll
    for (int rt = 0; rt < 4; rt++)
        #pragma unroll
        for (int ct = 0; ct < CT; ct++) acc[rt][ct] = (f32x4)0.0f;

    #pragma unroll
    for (int ks = 0; ks < KS; ks++) {
        const int kk = ks * 32;
        bf16x8 xb[4];
        #pragma unroll
        for (int rt = 0; rt < 4; rt++) xb[rt] = *(const bf16x8*)(&buf[rt * 16 + ar][kk + kg * 8]);
        #pragma unroll
        for (int ct = 0; ct < CT; ct++) {
            const float4* bp = (const float4*)(wiv + wbase + (long)(c0 + ct * 16 + ar) * D + kk + kg * 8);
            bf16x8 wf = cvt8(bp[0], bp[1]);
            #pragma unroll
            for (int rt = 0; rt < 4; rt++)
                acc[rt][ct] = __builtin_amdgcn_mfma_f32_16x16x32_bf16(wf, xb[rt], acc[rt][ct], 0, 0, 0);
        }
    }

    bf16x4 res[4][CT];
    #pragma unroll
    for (int ct = 0; ct < CT; ct++) {
        const int cb = c0 + ct * 16 + kg * 4;
        #pragma unroll
        for (int rt = 0; rt < 4; rt++)
            res[rt][ct] = *(const bf16x4*)(&buf[rt * 16 + ar][cb]);
    }
    __syncthreads();

    #pragma unroll
    for (int ct = 0; ct < CT; ct++) {
        const int cb = c0 + ct * 16 + kg * 4;
        const float4 bi4 = *(const float4*)(bi + g * D + cb);
        #pragma unroll
        for (int rt = 0; rt < 4; rt++) {
            bf16x4 hv;
            hv[0] = bfs(mish_f(acc[rt][ct][0] + bi4.x));
            hv[1] = bfs(mish_f(acc[rt][ct][1] + bi4.y));
            hv[2] = bfs(mish_f(acc[rt][ct][2] + bi4.z));
            hv[3] = bfs(mish_f(acc[rt][ct][3] + bi4.w));
            *(bf16x4*)(&buf[rt * 16 + ar][cb]) = hv;
        }
    }
    __syncthreads();

    #pragma unroll
    for (int rt = 0; rt < 4; rt++)
        #pragma unroll
        for (int ct = 0; ct < CT; ct++) acc[rt][ct] = (f32x4)0.0f;

    #pragma unroll
    for (int ks = 0; ks < KS; ks++) {
        const int kk = ks * 32;
        bf16x8 hb[4];
        #pragma unroll
        for (int rt = 0; rt < 4; rt++) hb[rt] = *(const bf16x8*)(&buf[rt * 16 + ar][kk + kg * 8]);
        #pragma unroll
        for (int ct = 0; ct < CT; ct++) {
            const float4* bp = (const float4*)(wov + wbase + (long)(c0 + ct * 16 + ar) * D + kk + kg * 8);
            bf16x8 wf = cvt8(bp[0], bp[1]);
            #pragma unroll
            for (int rt = 0; rt < 4; rt++)
                acc[rt][ct] = __builtin_amdgcn_mfma_f32_16x16x32_bf16(wf, hb[rt], acc[rt][ct], 0, 0, 0);
        }
    }

    {
        float* ob = out_msgs + (gFA + (long)f0 * A) * 64;
        #pragma unroll
        for (int ct = 0; ct < CT; ct++) {
            const int cb = c0 + ct * 16 + kg * 4;
            const float4 bo4 = *(const float4*)(bo + g * D + cb);
            #pragma unroll
            for (int rt = 0; rt < 4; rt++) {
                const int r = rt * 16 + ar;
                float4 o;
                o.x = acc[rt][ct][0] + bo4.x + b2f(res[rt][ct][0]);
                o.y = acc[rt][ct][1] + bo4.y + b2f(res[rt][ct][1]);
                o.z = acc[rt][ct][2] + bo4.z + b2f(res[rt][ct][2]);
                o.w = acc[rt][ct][3] + bo4.w + b2f(res[rt][ct][3]);
                if (r < valid) *(float4*)(ob + (long)r * D + cb) = o;
            }
        }
    }
}

extern "C" void kernel_launch(void* const* d_in, const int* in_sizes, int n_in,
                              void* d_out, int out_size, void* d_ws, size_t ws_size,
                              hipStream_t stream) {
    const float* emb_f = (const float*)d_in[0];
    const int Gs[4] = {2, 3, 2, 1};
    const int Ds[4] = {64, 128, 192, 256};

    const int*   idx_a[4];
    const float *wi_f[4], *bi_f[4], *wo_f[4], *bo_f[4];
    for (int k = 0; k < 4; k++) {
        idx_a[k] = (const int*)d_in[1 + 5 * k];
        wi_f[k]  = (const float*)d_in[2 + 5 * k];
        bi_f[k]  = (const float*)d_in[3 + 5 * k];
        wo_f[k]  = (const float*)d_in[4 + 5 * k];
        bo_f[k]  = (const float*)d_in[5 + 5 * k];
    }

    float* out = (float*)d_out;
    const long MSG_ELEMS = 115200000L;
    const long rowOff[4] = {0, 200000, 800000, 1400000};
    float* om[4]; float* oi[4];
    for (int k = 0; k < 4; k++) {
        om[k] = out + rowOff[k] * 64;
        oi[k] = out + MSG_ELEMS + rowOff[k];
    }

    const long EMB_ELEMS = 6400000L;
    long wPre[9]; wPre[0] = 0;
    int  wD[8];
    for (int k = 0; k < 4; k++) {
        long we = (long)Gs[k] * Ds[k] * Ds[k];
        wPre[2 * k + 1] = wPre[2 * k] + we;
        wPre[2 * k + 2] = wPre[2 * k + 1] + we;
        wD[2 * k] = Ds[k]; wD[2 * k + 1] = Ds[k];
    }
    const long NEED = (EMB_ELEMS + wPre[8]) * 2;

    if (ws_size >= (size_t)NEED) {
        __hip_bfloat16* emb_b = (__hip_bfloat16*)d_ws;
        __hip_bfloat16* w_b   = emb_b + EMB_ELEMS;

        CvtA ca;
        for (int k = 0; k < 4; k++) { ca.src[2 * k] = wi_f[k]; ca.src[2 * k + 1] = wo_f[k]; }
        for (int j = 0; j < 9; j++) ca.pre[j] = wPre[j];
        for (int j = 0; j < 8; j++) ca.Dv[j] = wD[j];
        ca.emb = emb_f;
        ca.embElems = EMB_ELEMS;
        long totChunks = (EMB_ELEMS + wPre[8]) / 8;
        cvt_all<<<dim3((totChunks + 255) / 256), dim3(256), 0, stream>>>(ca, emb_b);

        const __hip_bfloat16 *wi_b[4], *wo_b[4];
        for (int k = 0; k < 4; k++) { wi_b[k] = w_b + wPre[2 * k]; wo_b[k] = w_b + wPre[2 * k + 1]; }

        msg3_kernel<64, 1, 4><<<dim3(NB, 2), 256, 0, stream>>>(
            emb_b, idx_a[0], wi_b[0], bi_f[0], wo_b[0], bo_f[0], om[0], oi[0]);
        msg3_kernel<128, 2, 4><<<dim3(NB, 3), 256, 0, stream>>>(
            emb_b, idx_a[1], wi_b[1], bi_f[1], wo_b[1], bo_f[1], om[1], oi[1]);
        msg3_kernel<192, 3, 4><<<dim3(NB, 2), 256, 0, stream>>>(
            emb_b, idx_a[2], wi_b[2], bi_f[2], wo_b[2], bo_f[2], om[2], oi[2]);
        msg3_kernel<256, 4, 3><<<dim3(NB, 1), 256, 0, stream>>>(
            emb_b, idx_a[3], wi_b[3], bi_f[3], wo_b[3], bo_f[3], om[3], oi[3]);
    } else {
        msg_kernel<64, 1, 4><<<dim3(NB, 2), 256, 0, stream>>>(
            emb_f, idx_a[0], wi_f[0], bi_f[0], wo_f[0], bo_f[0], om[0], oi[0]);
        msg_kernel<128, 2, 4><<<dim3(NB, 3), 256, 0, stream>>>(
            emb_f, idx_a[1], wi_f[1], bi_f[1], wo_f[1], bo_f[1], om[1], oi[1]);
        msg_kernel<192, 3, 4><<<dim3(NB, 2), 256, 0, stream>>>(
            emb_f, idx_a[2], wi_f[2], bi_f[2], wo_f[2], bo_f[2], om[2], oi[2]);
        msg_kernel<256, 4, 3><<<dim3(NB, 1), 256, 0, stream>>>(
            emb_f, idx_a[3], wi_f[3], bi_f[3], wo_f[3], bo_f[3], om[3], oi[3]);
    }
}

// Round 13
// 200.265 us; speedup vs baseline: 2.1994x; 1.0352x over previous
//
#include <hip/hip_runtime.h>
#include <hip/hip_bf16.h>

#define NF 100000
#define TM 64
#define NB 1563   // ceil(NF/TM)

typedef __attribute__((ext_vector_type(8))) short bf16x8;
typedef __attribute__((ext_vector_type(4))) short bf16x4;
typedef __attribute__((ext_vector_type(4))) float f32x4;

__device__ __forceinline__ short bfs(float x) {
    union { __hip_bfloat16 h; short s; } u;
    u.h = __float2bfloat16(x);
    return u.s;
}

__device__ __forceinline__ float b2f(short s) {
    union { float f; unsigned u; } u;
    u.u = ((unsigned)(unsigned short)s) << 16;
    return u.f;
}

__device__ __forceinline__ bf16x8 cvt8(const float4 a, const float4 b) {
    bf16x8 r;
    r[0] = bfs(a.x); r[1] = bfs(a.y); r[2] = bfs(a.z); r[3] = bfs(a.w);
    r[4] = bfs(b.x); r[5] = bfs(b.y); r[6] = bfs(b.z); r[7] = bfs(b.w);
    return r;
}

__device__ __forceinline__ float mish_f(float v) {
    float t = __expf(v);
    float p = t * (t + 2.0f);
    float r = v * p * __builtin_amdgcn_rcpf(p + 2.0f);
    return (v > 20.0f) ? v : r;
}

// ---- merged fp32->bf16 conversion: embeddings (linear) + weights (K-slab) ----
// Weight repack: row-major [g][n][k] f32 -> K-slab bf16 [g][k/32][n][32]; a wave's
// wf fragment (lane=(ar,kg), slab ks) reads 1KB contiguous.
struct CvtA {
    const float* src[8];
    long pre[9];
    int  Dv[8];
    const float* emb;
    long embElems;
};

__global__ __launch_bounds__(256)
void cvt_all(CvtA a, __hip_bfloat16* __restrict__ dst) {
    long e = ((long)blockIdx.x * 256 + threadIdx.x) * 8;
    if (e < a.embElems) {
        const float4* s = (const float4*)(a.emb + e);
        *(bf16x8*)(dst + e) = cvt8(s[0], s[1]);
        return;
    }
    long we = e - a.embElems;
    if (we >= a.pre[8]) return;
    int j = 0;
    #pragma unroll
    for (int q = 0; q < 8; q++) if (we >= a.pre[q + 1]) j = q + 1;
    long le = we - a.pre[j];
    const int D = a.Dv[j];
    int g = (int)(le / ((long)D * D));
    int rem = (int)(le - (long)g * D * D);
    int n = rem / D;
    int k = rem - n * D;
    const float4* s = (const float4*)(a.src[j] + le);
    long off = a.embElems + a.pre[j] + (long)g * D * D + (long)(k >> 5) * 32 * D + n * 32 + (k & 31);
    *(bf16x8*)(dst + off) = cvt8(s[0], s[1]);
}

// ---- per-group body (R12 structure, register-dieted for a merged kernel) ----
// WMODE 0 (D<=128): full Wi/Wo preload in regs + register residual snapshot.
// WMODE 1 (D==192): 1-slab-ahead weight double-buffer; residual re-read from emb.
// WMODE 2 (D==256): plain in-loop K-slab weight loads (TLP hides); residual from emb.
template<int D, int A, int WMODE>
__device__ __forceinline__ void body(
    int fb, int g,
    const __hip_bfloat16* __restrict__ emb, const int* __restrict__ idx,
    const __hip_bfloat16* __restrict__ wi, const float* __restrict__ bi,
    const __hip_bfloat16* __restrict__ wo, const float* __restrict__ bo,
    float* __restrict__ out_msgs, float* __restrict__ out_idx,
    __hip_bfloat16* __restrict__ buf)
{
    constexpr int DP = D + 8;
    constexpr int CT = D / 64;
    constexpr int KS = D / 32;
    constexpr int RC = D / 8;
    constexpr int CH = (TM * RC) / 256;

    const int f0   = fb * TM;
    const int tid  = threadIdx.x;
    const int lane = tid & 63;
    const int w    = tid >> 6;
    const long gFA = (long)g * NF * A;
    const int valid = min(TM, NF - f0);
    const int* idx_g = idx + gFA + (long)f0 * A;

    const int ar = lane & 15;
    const int kg = lane >> 4;
    const int c0 = w * (D / 4);
    const long wlane = (long)g * D * D + (long)(c0 + ar) * 32 + kg * 8;

    // ---- gather with explicit MLP ----
    {
        int nodes[CH];
        #pragma unroll
        for (int j = 0; j < CH; j++) {
            int c = tid + j * 256;
            int r = c / RC;
            nodes[j] = (r < valid) ? idx_g[r * A + ((c % RC) >> 3)] : idx_g[0];
        }
        bf16x8 v[CH];
        #pragma unroll
        for (int j = 0; j < CH; j++) {
            int c = tid + j * 256;
            v[j] = *(const bf16x8*)(emb + (long)nodes[j] * 64 + (((c % RC) * 8) & 63));
        }
        #pragma unroll
        for (int j = 0; j < CH; j++) {
            int c = tid + j * 256;
            *(bf16x8*)(buf + (c / RC) * DP + (c % RC) * 8) = v[j];
        }
        if (tid < valid * A)
            __builtin_nontemporal_store((float)idx_g[tid], &out_idx[gFA + (long)f0 * A + tid]);
    }

    f32x4 acc[4][CT];
    #pragma unroll
    for (int rt = 0; rt < 4; rt++)
        #pragma unroll
        for (int ct = 0; ct < CT; ct++) acc[rt][ct] = (f32x4)0.0f;

    if constexpr (WMODE == 0) {
        // ---- full Wi preload (retires across the barrier) ----
        bf16x8 wia[KS][CT];
        #pragma unroll
        for (int ks = 0; ks < KS; ks++)
            #pragma unroll
            for (int ct = 0; ct < CT; ct++)
                wia[ks][ct] = *(const bf16x8*)(wi + wlane + (long)ks * 32 * D + ct * 512);

        __syncthreads();

        #pragma unroll
        for (int ks = 0; ks < KS; ks++) {
            const int kk = ks * 32;
            bf16x8 xb[4];
            #pragma unroll
            for (int rt = 0; rt < 4; rt++)
                xb[rt] = *(const bf16x8*)(buf + (rt * 16 + ar) * DP + kk + kg * 8);
            #pragma unroll
            for (int ct = 0; ct < CT; ct++)
                #pragma unroll
                for (int rt = 0; rt < 4; rt++)
                    acc[rt][ct] = __builtin_amdgcn_mfma_f32_16x16x32_bf16(wia[ks][ct], xb[rt], acc[rt][ct], 0, 0, 0);
        }

        // ---- full Wo preload (hides under res + barrier + mish) ----
        bf16x8 woa[KS][CT];
        #pragma unroll
        for (int ks = 0; ks < KS; ks++)
            #pragma unroll
            for (int ct = 0; ct < CT; ct++)
                woa[ks][ct] = *(const bf16x8*)(wo + wlane + (long)ks * 32 * D + ct * 512);

        bf16x4 res[4][CT];
        #pragma unroll
        for (int ct = 0; ct < CT; ct++) {
            const int cb = c0 + ct * 16 + kg * 4;
            #pragma unroll
            for (int rt = 0; rt < 4; rt++)
                res[rt][ct] = *(const bf16x4*)(buf + (rt * 16 + ar) * DP + cb);
        }
        __syncthreads();

        #pragma unroll
        for (int ct = 0; ct < CT; ct++) {
            const int cb = c0 + ct * 16 + kg * 4;
            const float4 bi4 = *(const float4*)(bi + g * D + cb);
            #pragma unroll
            for (int rt = 0; rt < 4; rt++) {
                bf16x4 hv;
                hv[0] = bfs(mish_f(acc[rt][ct][0] + bi4.x));
                hv[1] = bfs(mish_f(acc[rt][ct][1] + bi4.y));
                hv[2] = bfs(mish_f(acc[rt][ct][2] + bi4.z));
                hv[3] = bfs(mish_f(acc[rt][ct][3] + bi4.w));
                *(bf16x4*)(buf + (rt * 16 + ar) * DP + cb) = hv;
            }
        }
        __syncthreads();

        #pragma unroll
        for (int rt = 0; rt < 4; rt++)
            #pragma unroll
            for (int ct = 0; ct < CT; ct++) acc[rt][ct] = (f32x4)0.0f;

        #pragma unroll
        for (int ks = 0; ks < KS; ks++) {
            const int kk = ks * 32;
            bf16x8 hb[4];
            #pragma unroll
            for (int rt = 0; rt < 4; rt++)
                hb[rt] = *(const bf16x8*)(buf + (rt * 16 + ar) * DP + kk + kg * 8);
            #pragma unroll
            for (int ct = 0; ct < CT; ct++)
                #pragma unroll
                for (int rt = 0; rt < 4; rt++)
                    acc[rt][ct] = __builtin_amdgcn_mfma_f32_16x16x32_bf16(woa[ks][ct], hb[rt], acc[rt][ct], 0, 0, 0);
        }

        float* ob = out_msgs + (gFA + (long)f0 * A) * 64;
        #pragma unroll
        for (int ct = 0; ct < CT; ct++) {
            const int cb = c0 + ct * 16 + kg * 4;
            const float4 bo4 = *(const float4*)(bo + g * D + cb);
            #pragma unroll
            for (int rt = 0; rt < 4; rt++) {
                const int r = rt * 16 + ar;
                f32x4 o;
                o[0] = acc[rt][ct][0] + bo4.x + b2f(res[rt][ct][0]);
                o[1] = acc[rt][ct][1] + bo4.y + b2f(res[rt][ct][1]);
                o[2] = acc[rt][ct][2] + bo4.z + b2f(res[rt][ct][2]);
                o[3] = acc[rt][ct][3] + bo4.w + b2f(res[rt][ct][3]);
                if (r < valid)
                    __builtin_nontemporal_store(o, (f32x4*)(ob + (long)r * D + cb));
            }
        }
    } else {
        // ---- WMODE 1/2: GEMM1 with double-buffered or in-loop weights ----
        bf16x8 wcur[CT];
        if constexpr (WMODE == 1) {
            #pragma unroll
            for (int ct = 0; ct < CT; ct++)
                wcur[ct] = *(const bf16x8*)(wi + wlane + ct * 512);
        }
        __syncthreads();

        #pragma unroll
        for (int ks = 0; ks < KS; ks++) {
            const int kk = ks * 32;
            bf16x8 xb[4];
            #pragma unroll
            for (int rt = 0; rt < 4; rt++)
                xb[rt] = *(const bf16x8*)(buf + (rt * 16 + ar) * DP + kk + kg * 8);
            if constexpr (WMODE == 1) {
                bf16x8 wnx[CT];
                if (ks + 1 < KS)
                    #pragma unroll
                    for (int ct = 0; ct < CT; ct++)
                        wnx[ct] = *(const bf16x8*)(wi + wlane + (long)(ks + 1) * 32 * D + ct * 512);
                #pragma unroll
                for (int ct = 0; ct < CT; ct++)
                    #pragma unroll
                    for (int rt = 0; rt < 4; rt++)
                        acc[rt][ct] = __builtin_amdgcn_mfma_f32_16x16x32_bf16(wcur[ct], xb[rt], acc[rt][ct], 0, 0, 0);
                if (ks + 1 < KS)
                    #pragma unroll
                    for (int ct = 0; ct < CT; ct++) wcur[ct] = wnx[ct];
            } else {
                #pragma unroll
                for (int ct = 0; ct < CT; ct++) {
                    bf16x8 wf = *(const bf16x8*)(wi + wlane + (long)ks * 32 * D + ct * 512);
                    #pragma unroll
                    for (int rt = 0; rt < 4; rt++)
                        acc[rt][ct] = __builtin_amdgcn_mfma_f32_16x16x32_bf16(wf, xb[rt], acc[rt][ct], 0, 0, 0);
                }
            }
        }

        __syncthreads();   // all X reads complete before H overwrites buf

        #pragma unroll
        for (int ct = 0; ct < CT; ct++) {
            const int cb = c0 + ct * 16 + kg * 4;
            const float4 bi4 = *(const float4*)(bi + g * D + cb);
            #pragma unroll
            for (int rt = 0; rt < 4; rt++) {
                bf16x4 hv;
                hv[0] = bfs(mish_f(acc[rt][ct][0] + bi4.x));
                hv[1] = bfs(mish_f(acc[rt][ct][1] + bi4.y));
                hv[2] = bfs(mish_f(acc[rt][ct][2] + bi4.z));
                hv[3] = bfs(mish_f(acc[rt][ct][3] + bi4.w));
                *(bf16x4*)(buf + (rt * 16 + ar) * DP + cb) = hv;
            }
        }
        __syncthreads();

        #pragma unroll
        for (int rt = 0; rt < 4; rt++)
            #pragma unroll
            for (int ct = 0; ct < CT; ct++) acc[rt][ct] = (f32x4)0.0f;

        if constexpr (WMODE == 1) {
            #pragma unroll
            for (int ct = 0; ct < CT; ct++)
                wcur[ct] = *(const bf16x8*)(wo + wlane + ct * 512);
        }

        #pragma unroll
        for (int ks = 0; ks < KS; ks++) {
            const int kk = ks * 32;
            bf16x8 hb[4];
            #pragma unroll
            for (int rt = 0; rt < 4; rt++)
                hb[rt] = *(const bf16x8*)(buf + (rt * 16 + ar) * DP + kk + kg * 8);
            if constexpr (WMODE == 1) {
                bf16x8 wnx[CT];
                if (ks + 1 < KS)
                    #pragma unroll
                    for (int ct = 0; ct < CT; ct++)
                        wnx[ct] = *(const bf16x8*)(wo + wlane + (long)(ks + 1) * 32 * D + ct * 512);
                #pragma unroll
                for (int ct = 0; ct < CT; ct++)
                    #pragma unroll
                    for (int rt = 0; rt < 4; rt++)
                        acc[rt][ct] = __builtin_amdgcn_mfma_f32_16x16x32_bf16(wcur[ct], hb[rt], acc[rt][ct], 0, 0, 0);
                if (ks + 1 < KS)
                    #pragma unroll
                    for (int ct = 0; ct < CT; ct++) wcur[ct] = wnx[ct];
            } else {
                #pragma unroll
                for (int ct = 0; ct < CT; ct++) {
                    bf16x8 wf = *(const bf16x8*)(wo + wlane + (long)ks * 32 * D + ct * 512);
                    #pragma unroll
                    for (int rt = 0; rt < 4; rt++)
                        acc[rt][ct] = __builtin_amdgcn_mfma_f32_16x16x32_bf16(wf, hb[rt], acc[rt][ct], 0, 0, 0);
                }
            }
        }

        // ---- epilogue 2: residual re-read from emb (bit-identical bf16) ----
        float* ob = out_msgs + (gFA + (long)f0 * A) * 64;
        #pragma unroll
        for (int ct = 0; ct < CT; ct++) {
            const int cb = c0 + ct * 16 + kg * 4;
            const int sres = (c0 + ct * 16) >> 6;   // kg*4 never crosses a 64-elem segment
            const float4 bo4 = *(const float4*)(bo + g * D + cb);
            #pragma unroll
            for (int rt = 0; rt < 4; rt++) {
                const int r = rt * 16 + ar;
                int node = idx_g[min(r, valid - 1) * A + sres];
                bf16x4 xv = *(const bf16x4*)(emb + (long)node * 64 + (cb & 63));
                f32x4 o;
                o[0] = acc[rt][ct][0] + bo4.x + b2f(xv[0]);
                o[1] = acc[rt][ct][1] + bo4.y + b2f(xv[1]);
                o[2] = acc[rt][ct][2] + bo4.z + b2f(xv[2]);
                o[3] = acc[rt][ct][3] + bo4.w + b2f(xv[3]);
                if (r < valid)
                    __builtin_nontemporal_store(o, (f32x4*)(ob + (long)r * D + cb));
            }
        }
    }
}

struct KArgs {
    const __hip_bfloat16* emb;
    const int* idx[4];
    const __hip_bfloat16* wi[4]; const float* bi[4];
    const __hip_bfloat16* wo[4]; const float* bo[4];
    float* om[4]; float* oi[4];
};

// Single merged kernel: D=256 range first, then 192, 128, 64.
__global__ __launch_bounds__(256, 4)
void fused_kernel(KArgs a) {
    __shared__ __hip_bfloat16 buf[TM * 264];   // sized for D=256 (DP=264), 33.8 KB
    const int b = blockIdx.x;
    if (b < NB) {
        body<256, 4, 2>(b, 0, a.emb, a.idx[3], a.wi[3], a.bi[3], a.wo[3], a.bo[3], a.om[3], a.oi[3], buf);
    } else if (b < NB * 3) {
        int r = b - NB;
        body<192, 3, 1>(r % NB, r / NB, a.emb, a.idx[2], a.wi[2], a.bi[2], a.wo[2], a.bo[2], a.om[2], a.oi[2], buf);
    } else if (b < NB * 6) {
        int r = b - NB * 3;
        body<128, 2, 0>(r % NB, r / NB, a.emb, a.idx[1], a.wi[1], a.bi[1], a.wo[1], a.bo[1], a.om[1], a.oi[1], buf);
    } else {
        int r = b - NB * 6;
        body<64, 1, 0>(r % NB, r / NB, a.emb, a.idx[0], a.wi[0], a.bi[0], a.wo[0], a.bo[0], a.om[0], a.oi[0], buf);
    }
}

// ---- fallback (ws too small): on-the-fly f32 path, row-major weights ----
template<int D, int A, int MINW>
__global__ __launch_bounds__(256, MINW)
void msg_kernel(const float* __restrict__ embv,
                const int* __restrict__ idx,
                const float* __restrict__ wiv, const float* __restrict__ bi,
                const float* __restrict__ wov, const float* __restrict__ bo,
                float* __restrict__ out_msgs, float* __restrict__ out_idx)
{
    constexpr int DP = D + 8;
    constexpr int CT = D / 64;
    constexpr int KS = D / 32;
    constexpr int RC = D / 8;
    __shared__ __hip_bfloat16 buf[TM][DP];

    const int g    = blockIdx.y;
    const int f0   = blockIdx.x * TM;
    const int tid  = threadIdx.x;
    const int lane = tid & 63;
    const int w    = tid >> 6;
    const long gFA = (long)g * NF * A;
    const int valid = min(TM, NF - f0);

    {
        const int* idx_g = idx + gFA + (long)f0 * A;
        #pragma unroll
        for (int c = tid; c < TM * RC; c += 256) {
            int r = c / RC;
            int i = (c - r * RC) * 8;
            bf16x8 v = (bf16x8)0;
            if (r < valid) {
                int node = idx_g[r * A + (i >> 6)];
                const float4* s = (const float4*)(embv + (long)node * 64 + (i & 63));
                v = cvt8(s[0], s[1]);
            }
            *(bf16x8*)(&buf[r][i]) = v;
        }
        if (tid < valid * A) out_idx[gFA + (long)f0 * A + tid] = (float)idx_g[tid];
    }
    __syncthreads();

    const int ar = lane & 15;
    const int kg = lane >> 4;
    const int c0 = w * (D / 4);
    const long wbase = (long)g * D * D;

    f32x4 acc[4][CT];
    #pragma unroll
    for (int rt = 0; rt < 4; rt++)
        #pragma unroll
        for (int ct = 0; ct < CT; ct++) acc[rt][ct] = (f32x4)0.0f;

    #pragma unroll
    for (int ks = 0; ks < KS; ks++) {
        const int kk = ks * 32;
        bf16x8 xb[4];
        #pragma unroll
        for (int rt = 0; rt < 4; rt++) xb[rt] = *(const bf16x8*)(&buf[rt * 16 + ar][kk + kg * 8]);
        #pragma unroll
        for (int ct = 0; ct < CT; ct++) {
            const float4* bp = (const float4*)(wiv + wbase + (long)(c0 + ct * 16 + ar) * D + kk + kg * 8);
            bf16x8 wf = cvt8(bp[0], bp[1]);
            #pragma unroll
            for (int rt = 0; rt < 4; rt++)
                acc[rt][ct] = __builtin_amdgcn_mfma_f32_16x16x32_bf16(wf, xb[rt], acc[rt][ct], 0, 0, 0);
        }
    }

    bf16x4 res[4][CT];
    #pragma unroll
    for (int ct = 0; ct < CT; ct++) {
        const int cb = c0 + ct * 16 + kg * 4;
        #pragma unroll
        for (int rt = 0; rt < 4; rt++)
            res[rt][ct] = *(const bf16x4*)(&buf[rt * 16 + ar][cb]);
    }
    __syncthreads();

    #pragma unroll
    for (int ct = 0; ct < CT; ct++) {
        const int cb = c0 + ct * 16 + kg * 4;
        const float4 bi4 = *(const float4*)(bi + g * D + cb);
        #pragma unroll
        for (int rt = 0; rt < 4; rt++) {
            bf16x4 hv;
            hv[0] = bfs(mish_f(acc[rt][ct][0] + bi4.x));
            hv[1] = bfs(mish_f(acc[rt][ct][1] + bi4.y));
            hv[2] = bfs(mish_f(acc[rt][ct][2] + bi4.z));
            hv[3] = bfs(mish_f(acc[rt][ct][3] + bi4.w));
            *(bf16x4*)(&buf[rt * 16 + ar][cb]) = hv;
        }
    }
    __syncthreads();

    #pragma unroll
    for (int rt = 0; rt < 4; rt++)
        #pragma unroll
        for (int ct = 0; ct < CT; ct++) acc[rt][ct] = (f32x4)0.0f;

    #pragma unroll
    for (int ks = 0; ks < KS; ks++) {
        const int kk = ks * 32;
        bf16x8 hb[4];
        #pragma unroll
        for (int rt = 0; rt < 4; rt++) hb[rt] = *(const bf16x8*)(&buf[rt * 16 + ar][kk + kg * 8]);
        #pragma unroll
        for (int ct = 0; ct < CT; ct++) {
            const float4* bp = (const float4*)(wov + wbase + (long)(c0 + ct * 16 + ar) * D + kk + kg * 8);
            bf16x8 wf = cvt8(bp[0], bp[1]);
            #pragma unroll
            for (int rt = 0; rt < 4; rt++)
                acc[rt][ct] = __builtin_amdgcn_mfma_f32_16x16x32_bf16(wf, hb[rt], acc[rt][ct], 0, 0, 0);
        }
    }

    {
        float* ob = out_msgs + (gFA + (long)f0 * A) * 64;
        #pragma unroll
        for (int ct = 0; ct < CT; ct++) {
            const int cb = c0 + ct * 16 + kg * 4;
            const float4 bo4 = *(const float4*)(bo + g * D + cb);
            #pragma unroll
            for (int rt = 0; rt < 4; rt++) {
                const int r = rt * 16 + ar;
                float4 o;
                o.x = acc[rt][ct][0] + bo4.x + b2f(res[rt][ct][0]);
                o.y = acc[rt][ct][1] + bo4.y + b2f(res[rt][ct][1]);
                o.z = acc[rt][ct][2] + bo4.z + b2f(res[rt][ct][2]);
                o.w = acc[rt][ct][3] + bo4.w + b2f(res[rt][ct][3]);
                if (r < valid) *(float4*)(ob + (long)r * D + cb) = o;
            }
        }
    }
}

extern "C" void kernel_launch(void* const* d_in, const int* in_sizes, int n_in,
                              void* d_out, int out_size, void* d_ws, size_t ws_size,
                              hipStream_t stream) {
    const float* emb_f = (const float*)d_in[0];
    const int Gs[4] = {2, 3, 2, 1};
    const int Ds[4] = {64, 128, 192, 256};

    const int*   idx_a[4];
    const float *wi_f[4], *bi_f[4], *wo_f[4], *bo_f[4];
    for (int k = 0; k < 4; k++) {
        idx_a[k] = (const int*)d_in[1 + 5 * k];
        wi_f[k]  = (const float*)d_in[2 + 5 * k];
        bi_f[k]  = (const float*)d_in[3 + 5 * k];
        wo_f[k]  = (const float*)d_in[4 + 5 * k];
        bo_f[k]  = (const float*)d_in[5 + 5 * k];
    }

    float* out = (float*)d_out;
    const long MSG_ELEMS = 115200000L;
    const long rowOff[4] = {0, 200000, 800000, 1400000};
    float* om[4]; float* oi[4];
    for (int k = 0; k < 4; k++) {
        om[k] = out + rowOff[k] * 64;
        oi[k] = out + MSG_ELEMS + rowOff[k];
    }

    const long EMB_ELEMS = 6400000L;
    long wPre[9]; wPre[0] = 0;
    int  wD[8];
    for (int k = 0; k < 4; k++) {
        long we = (long)Gs[k] * Ds[k] * Ds[k];
        wPre[2 * k + 1] = wPre[2 * k] + we;
        wPre[2 * k + 2] = wPre[2 * k + 1] + we;
        wD[2 * k] = Ds[k]; wD[2 * k + 1] = Ds[k];
    }
    const long NEED = (EMB_ELEMS + wPre[8]) * 2;

    if (ws_size >= (size_t)NEED) {
        __hip_bfloat16* emb_b = (__hip_bfloat16*)d_ws;
        __hip_bfloat16* w_b   = emb_b + EMB_ELEMS;

        CvtA ca;
        for (int k = 0; k < 4; k++) { ca.src[2 * k] = wi_f[k]; ca.src[2 * k + 1] = wo_f[k]; }
        for (int j = 0; j < 9; j++) ca.pre[j] = wPre[j];
        for (int j = 0; j < 8; j++) ca.Dv[j] = wD[j];
        ca.emb = emb_f;
        ca.embElems = EMB_ELEMS;
        long totChunks = (EMB_ELEMS + wPre[8]) / 8;
        cvt_all<<<dim3((totChunks + 255) / 256), dim3(256), 0, stream>>>(ca, emb_b);

        KArgs a;
        a.emb = emb_b;
        for (int k = 0; k < 4; k++) {
            a.idx[k] = idx_a[k];
            a.wi[k] = w_b + wPre[2 * k];
            a.wo[k] = w_b + wPre[2 * k + 1];
            a.bi[k] = bi_f[k];
            a.bo[k] = bo_f[k];
            a.om[k] = om[k];
            a.oi[k] = oi[k];
        }
        fused_kernel<<<dim3(NB * 8), dim3(256), 0, stream>>>(a);
    } else {
        msg_kernel<64, 1, 4><<<dim3(NB, 2), 256, 0, stream>>>(
            emb_f, idx_a[0], wi_f[0], bi_f[0], wo_f[0], bo_f[0], om[0], oi[0]);
        msg_kernel<128, 2, 4><<<dim3(NB, 3), 256, 0, stream>>>(
            emb_f, idx_a[1], wi_f[1], bi_f[1], wo_f[1], bo_f[1], om[1], oi[1]);
        msg_kernel<192, 3, 4><<<dim3(NB, 2), 256, 0, stream>>>(
            emb_f, idx_a[2], wi_f[2], bi_f[2], wo_f[2], bo_f[2], om[2], oi[2]);
        msg_kernel<256, 4, 3><<<dim3(NB, 1), 256, 0, stream>>>(
            emb_f, idx_a[3], wi_f[3], bi_f[3], wo_f[3], bo_f[3], om[3], oi[3]);
    }
}

// Round 14
// 198.296 us; speedup vs baseline: 2.2212x; 1.0099x over previous
//
#include <hip/hip_runtime.h>
#include <hip/hip_bf16.h>

#define NF 100000
#define TM 64
#define NB 1563   // ceil(NF/TM)

typedef __attribute__((ext_vector_type(8))) short bf16x8;
typedef __attribute__((ext_vector_type(4))) short bf16x4;
typedef __attribute__((ext_vector_type(4))) float f32x4;

__device__ __forceinline__ short bfs(float x) {
    union { __hip_bfloat16 h; short s; } u;
    u.h = __float2bfloat16(x);
    return u.s;
}

__device__ __forceinline__ float b2f(short s) {
    union { float f; unsigned u; } u;
    u.u = ((unsigned)(unsigned short)s) << 16;
    return u.f;
}

__device__ __forceinline__ bf16x8 cvt8(const float4 a, const float4 b) {
    bf16x8 r;
    r[0] = bfs(a.x); r[1] = bfs(a.y); r[2] = bfs(a.z); r[3] = bfs(a.w);
    r[4] = bfs(b.x); r[5] = bfs(b.y); r[6] = bfs(b.z); r[7] = bfs(b.w);
    return r;
}

__device__ __forceinline__ float mish_f(float v) {
    float t = __expf(v);
    float p = t * (t + 2.0f);
    float r = v * p * __builtin_amdgcn_rcpf(p + 2.0f);
    return (v > 20.0f) ? v : r;
}

// ---- merged fp32->bf16 conversion: embeddings (linear) + weights (K-slab) ----
struct CvtA {
    const float* src[8];
    long pre[9];
    int  Dv[8];
    const float* emb;
    long embElems;
};

__global__ __launch_bounds__(256)
void cvt_all(CvtA a, __hip_bfloat16* __restrict__ dst) {
    long e = ((long)blockIdx.x * 256 + threadIdx.x) * 8;
    if (e < a.embElems) {
        const float4* s = (const float4*)(a.emb + e);
        *(bf16x8*)(dst + e) = cvt8(s[0], s[1]);
        return;
    }
    long we = e - a.embElems;
    if (we >= a.pre[8]) return;
    int j = 0;
    #pragma unroll
    for (int q = 0; q < 8; q++) if (we >= a.pre[q + 1]) j = q + 1;
    long le = we - a.pre[j];
    const int D = a.Dv[j];
    int g = (int)(le / ((long)D * D));
    int rem = (int)(le - (long)g * D * D);
    int n = rem / D;
    int k = rem - n * D;
    const float4* s = (const float4*)(a.src[j] + le);
    long off = a.embElems + a.pre[j] + (long)g * D * D + (long)(k >> 5) * 32 * D + n * 32 + (k & 31);
    *(bf16x8*)(dst + off) = cvt8(s[0], s[1]);
}

// ---- per-group body ----
// WMODE 0 (D<=128): full Wi/Wo preload in regs; SEPARATE X/H LDS regions ->
//                   only 2 barriers, residual read from intact X region.
// WMODE 1 (D==192): 1-slab-ahead weight double-buffer; residual re-read from emb.
// WMODE 2 (D==256): plain in-loop K-slab weight loads; residual re-read from emb.
template<int D, int A, int WMODE>
__device__ __forceinline__ void body(
    int fb, int g,
    const __hip_bfloat16* __restrict__ emb, const int* __restrict__ idx,
    const __hip_bfloat16* __restrict__ wi, const float* __restrict__ bi,
    const __hip_bfloat16* __restrict__ wo, const float* __restrict__ bo,
    float* __restrict__ out_msgs, float* __restrict__ out_idx,
    __hip_bfloat16* __restrict__ buf)
{
    constexpr int DP = D + 8;
    constexpr int CT = D / 64;
    constexpr int KS = D / 32;
    constexpr int RC = D / 8;
    constexpr int CH = (TM * RC) / 256;

    const int f0   = fb * TM;
    const int tid  = threadIdx.x;
    const int lane = tid & 63;
    const int w    = tid >> 6;
    const long gFA = (long)g * NF * A;
    const int valid = min(TM, NF - f0);
    const int* idx_g = idx + gFA + (long)f0 * A;

    const int ar = lane & 15;
    const int kg = lane >> 4;
    const int c0 = w * (D / 4);
    const long wlane = (long)g * D * D + (long)(c0 + ar) * 32 + kg * 8;

    __hip_bfloat16* X = buf;                    // X region
    __hip_bfloat16* H = (WMODE == 0) ? buf + TM * DP : buf;   // separate H for small D

    // ---- gather with explicit MLP ----
    {
        int nodes[CH];
        #pragma unroll
        for (int j = 0; j < CH; j++) {
            int c = tid + j * 256;
            int r = c / RC;
            nodes[j] = (r < valid) ? idx_g[r * A + ((c % RC) >> 3)] : idx_g[0];
        }
        bf16x8 v[CH];
        #pragma unroll
        for (int j = 0; j < CH; j++) {
            int c = tid + j * 256;
            v[j] = *(const bf16x8*)(emb + (long)nodes[j] * 64 + (((c % RC) * 8) & 63));
        }
        #pragma unroll
        for (int j = 0; j < CH; j++) {
            int c = tid + j * 256;
            *(bf16x8*)(X + (c / RC) * DP + (c % RC) * 8) = v[j];
        }
        if (tid < valid * A)
            __builtin_nontemporal_store((float)idx_g[tid], &out_idx[gFA + (long)f0 * A + tid]);
    }

    f32x4 acc[4][CT];
    #pragma unroll
    for (int rt = 0; rt < 4; rt++)
        #pragma unroll
        for (int ct = 0; ct < CT; ct++) acc[rt][ct] = (f32x4)0.0f;

    if constexpr (WMODE == 0) {
        // ---- full Wi preload (retires across the barrier) ----
        bf16x8 wia[KS][CT];
        #pragma unroll
        for (int ks = 0; ks < KS; ks++)
            #pragma unroll
            for (int ct = 0; ct < CT; ct++)
                wia[ks][ct] = *(const bf16x8*)(wi + wlane + (long)ks * 32 * D + ct * 512);

        __syncthreads();   // barrier 1: X visible

        #pragma unroll
        for (int ks = 0; ks < KS; ks++) {
            const int kk = ks * 32;
            bf16x8 xb[4];
            #pragma unroll
            for (int rt = 0; rt < 4; rt++)
                xb[rt] = *(const bf16x8*)(X + (rt * 16 + ar) * DP + kk + kg * 8);
            __builtin_amdgcn_s_setprio(1);
            #pragma unroll
            for (int ct = 0; ct < CT; ct++)
                #pragma unroll
                for (int rt = 0; rt < 4; rt++)
                    acc[rt][ct] = __builtin_amdgcn_mfma_f32_16x16x32_bf16(wia[ks][ct], xb[rt], acc[rt][ct], 0, 0, 0);
            __builtin_amdgcn_s_setprio(0);
        }

        // ---- full Wo preload (hides under mish) ----
        bf16x8 woa[KS][CT];
        #pragma unroll
        for (int ks = 0; ks < KS; ks++)
            #pragma unroll
            for (int ct = 0; ct < CT; ct++)
                woa[ks][ct] = *(const bf16x8*)(wo + wlane + (long)ks * 32 * D + ct * 512);

        // ---- mish -> H region (no barrier needed: disjoint from X) ----
        #pragma unroll
        for (int ct = 0; ct < CT; ct++) {
            const int cb = c0 + ct * 16 + kg * 4;
            const float4 bi4 = *(const float4*)(bi + g * D + cb);
            #pragma unroll
            for (int rt = 0; rt < 4; rt++) {
                bf16x4 hv;
                hv[0] = bfs(mish_f(acc[rt][ct][0] + bi4.x));
                hv[1] = bfs(mish_f(acc[rt][ct][1] + bi4.y));
                hv[2] = bfs(mish_f(acc[rt][ct][2] + bi4.z));
                hv[3] = bfs(mish_f(acc[rt][ct][3] + bi4.w));
                *(bf16x4*)(H + (rt * 16 + ar) * DP + cb) = hv;
            }
        }
        __syncthreads();   // barrier 2: H visible

        #pragma unroll
        for (int rt = 0; rt < 4; rt++)
            #pragma unroll
            for (int ct = 0; ct < CT; ct++) acc[rt][ct] = (f32x4)0.0f;

        #pragma unroll
        for (int ks = 0; ks < KS; ks++) {
            const int kk = ks * 32;
            bf16x8 hb[4];
            #pragma unroll
            for (int rt = 0; rt < 4; rt++)
                hb[rt] = *(const bf16x8*)(H + (rt * 16 + ar) * DP + kk + kg * 8);
            __builtin_amdgcn_s_setprio(1);
            #pragma unroll
            for (int ct = 0; ct < CT; ct++)
                #pragma unroll
                for (int rt = 0; rt < 4; rt++)
                    acc[rt][ct] = __builtin_amdgcn_mfma_f32_16x16x32_bf16(woa[ks][ct], hb[rt], acc[rt][ct], 0, 0, 0);
            __builtin_amdgcn_s_setprio(0);
        }

        // ---- epilogue 2: residual straight from intact X region ----
        float* ob = out_msgs + (gFA + (long)f0 * A) * 64;
        #pragma unroll
        for (int ct = 0; ct < CT; ct++) {
            const int cb = c0 + ct * 16 + kg * 4;
            const float4 bo4 = *(const float4*)(bo + g * D + cb);
            #pragma unroll
            for (int rt = 0; rt < 4; rt++) {
                const int r = rt * 16 + ar;
                bf16x4 xv = *(const bf16x4*)(X + (rt * 16 + ar) * DP + cb);
                f32x4 o;
                o[0] = acc[rt][ct][0] + bo4.x + b2f(xv[0]);
                o[1] = acc[rt][ct][1] + bo4.y + b2f(xv[1]);
                o[2] = acc[rt][ct][2] + bo4.z + b2f(xv[2]);
                o[3] = acc[rt][ct][3] + bo4.w + b2f(xv[3]);
                if (r < valid)
                    __builtin_nontemporal_store(o, (f32x4*)(ob + (long)r * D + cb));
            }
        }
    } else {
        // ---- WMODE 1/2: single-buffer, 3 barriers ----
        bf16x8 wcur[CT];
        if constexpr (WMODE == 1) {
            #pragma unroll
            for (int ct = 0; ct < CT; ct++)
                wcur[ct] = *(const bf16x8*)(wi + wlane + ct * 512);
        }
        __syncthreads();

        #pragma unroll
        for (int ks = 0; ks < KS; ks++) {
            const int kk = ks * 32;
            bf16x8 xb[4];
            #pragma unroll
            for (int rt = 0; rt < 4; rt++)
                xb[rt] = *(const bf16x8*)(X + (rt * 16 + ar) * DP + kk + kg * 8);
            if constexpr (WMODE == 1) {
                bf16x8 wnx[CT];
                if (ks + 1 < KS)
                    #pragma unroll
                    for (int ct = 0; ct < CT; ct++)
                        wnx[ct] = *(const bf16x8*)(wi + wlane + (long)(ks + 1) * 32 * D + ct * 512);
                __builtin_amdgcn_s_setprio(1);
                #pragma unroll
                for (int ct = 0; ct < CT; ct++)
                    #pragma unroll
                    for (int rt = 0; rt < 4; rt++)
                        acc[rt][ct] = __builtin_amdgcn_mfma_f32_16x16x32_bf16(wcur[ct], xb[rt], acc[rt][ct], 0, 0, 0);
                __builtin_amdgcn_s_setprio(0);
                if (ks + 1 < KS)
                    #pragma unroll
                    for (int ct = 0; ct < CT; ct++) wcur[ct] = wnx[ct];
            } else {
                bf16x8 wf[CT];
                #pragma unroll
                for (int ct = 0; ct < CT; ct++)
                    wf[ct] = *(const bf16x8*)(wi + wlane + (long)ks * 32 * D + ct * 512);
                __builtin_amdgcn_s_setprio(1);
                #pragma unroll
                for (int ct = 0; ct < CT; ct++)
                    #pragma unroll
                    for (int rt = 0; rt < 4; rt++)
                        acc[rt][ct] = __builtin_amdgcn_mfma_f32_16x16x32_bf16(wf[ct], xb[rt], acc[rt][ct], 0, 0, 0);
                __builtin_amdgcn_s_setprio(0);
            }
        }

        __syncthreads();   // all X reads complete before H overwrites buf

        #pragma unroll
        for (int ct = 0; ct < CT; ct++) {
            const int cb = c0 + ct * 16 + kg * 4;
            const float4 bi4 = *(const float4*)(bi + g * D + cb);
            #pragma unroll
            for (int rt = 0; rt < 4; rt++) {
                bf16x4 hv;
                hv[0] = bfs(mish_f(acc[rt][ct][0] + bi4.x));
                hv[1] = bfs(mish_f(acc[rt][ct][1] + bi4.y));
                hv[2] = bfs(mish_f(acc[rt][ct][2] + bi4.z));
                hv[3] = bfs(mish_f(acc[rt][ct][3] + bi4.w));
                *(bf16x4*)(H + (rt * 16 + ar) * DP + cb) = hv;
            }
        }
        __syncthreads();

        #pragma unroll
        for (int rt = 0; rt < 4; rt++)
            #pragma unroll
            for (int ct = 0; ct < CT; ct++) acc[rt][ct] = (f32x4)0.0f;

        if constexpr (WMODE == 1) {
            #pragma unroll
            for (int ct = 0; ct < CT; ct++)
                wcur[ct] = *(const bf16x8*)(wo + wlane + ct * 512);
        }

        #pragma unroll
        for (int ks = 0; ks < KS; ks++) {
            const int kk = ks * 32;
            bf16x8 hb[4];
            #pragma unroll
            for (int rt = 0; rt < 4; rt++)
                hb[rt] = *(const bf16x8*)(H + (rt * 16 + ar) * DP + kk + kg * 8);
            if constexpr (WMODE == 1) {
                bf16x8 wnx[CT];
                if (ks + 1 < KS)
                    #pragma unroll
                    for (int ct = 0; ct < CT; ct++)
                        wnx[ct] = *(const bf16x8*)(wo + wlane + (long)(ks + 1) * 32 * D + ct * 512);
                __builtin_amdgcn_s_setprio(1);
                #pragma unroll
                for (int ct = 0; ct < CT; ct++)
                    #pragma unroll
                    for (int rt = 0; rt < 4; rt++)
                        acc[rt][ct] = __builtin_amdgcn_mfma_f32_16x16x32_bf16(wcur[ct], hb[rt], acc[rt][ct], 0, 0, 0);
                __builtin_amdgcn_s_setprio(0);
                if (ks + 1 < KS)
                    #pragma unroll
                    for (int ct = 0; ct < CT; ct++) wcur[ct] = wnx[ct];
            } else {
                bf16x8 wf[CT];
                #pragma unroll
                for (int ct = 0; ct < CT; ct++)
                    wf[ct] = *(const bf16x8*)(wo + wlane + (long)ks * 32 * D + ct * 512);
                __builtin_amdgcn_s_setprio(1);
                #pragma unroll
                for (int ct = 0; ct < CT; ct++)
                    #pragma unroll
                    for (int rt = 0; rt < 4; rt++)
                        acc[rt][ct] = __builtin_amdgcn_mfma_f32_16x16x32_bf16(wf[ct], hb[rt], acc[rt][ct], 0, 0, 0);
                __builtin_amdgcn_s_setprio(0);
            }
        }

        // ---- epilogue 2: residual re-read from emb (bit-identical bf16) ----
        float* ob = out_msgs + (gFA + (long)f0 * A) * 64;
        #pragma unroll
        for (int ct = 0; ct < CT; ct++) {
            const int cb = c0 + ct * 16 + kg * 4;
            const int sres = (c0 + ct * 16) >> 6;
            const float4 bo4 = *(const float4*)(bo + g * D + cb);
            #pragma unroll
            for (int rt = 0; rt < 4; rt++) {
                const int r = rt * 16 + ar;
                int node = idx_g[min(r, valid - 1) * A + sres];
                bf16x4 xv = *(const bf16x4*)(emb + (long)node * 64 + (cb & 63));
                f32x4 o;
                o[0] = acc[rt][ct][0] + bo4.x + b2f(xv[0]);
                o[1] = acc[rt][ct][1] + bo4.y + b2f(xv[1]);
                o[2] = acc[rt][ct][2] + bo4.z + b2f(xv[2]);
                o[3] = acc[rt][ct][3] + bo4.w + b2f(xv[3]);
                if (r < valid)
                    __builtin_nontemporal_store(o, (f32x4*)(ob + (long)r * D + cb));
            }
        }
    }
}

struct KArgs {
    const __hip_bfloat16* emb;
    const int* idx[4];
    const __hip_bfloat16* wi[4]; const float* bi[4];
    const __hip_bfloat16* wo[4]; const float* bo[4];
    float* om[4]; float* oi[4];
};

// Single merged kernel: D=256 range first, then 192, 128, 64.
// LDS 34816B: holds D=256 single region (64x264x2=33792) OR two D<=128 regions
// (2x64x136x2=34816). 4 blocks/CU -> 139KB of 160KB.
__global__ __launch_bounds__(256, 4)
void fused_kernel(KArgs a) {
    __shared__ __hip_bfloat16 buf[2 * TM * 136];
    const int b = blockIdx.x;
    if (b < NB) {
        body<256, 4, 2>(b, 0, a.emb, a.idx[3], a.wi[3], a.bi[3], a.wo[3], a.bo[3], a.om[3], a.oi[3], buf);
    } else if (b < NB * 3) {
        int r = b - NB;
        body<192, 3, 1>(r % NB, r / NB, a.emb, a.idx[2], a.wi[2], a.bi[2], a.wo[2], a.bo[2], a.om[2], a.oi[2], buf);
    } else if (b < NB * 6) {
        int r = b - NB * 3;
        body<128, 2, 0>(r % NB, r / NB, a.emb, a.idx[1], a.wi[1], a.bi[1], a.wo[1], a.bo[1], a.om[1], a.oi[1], buf);
    } else {
        int r = b - NB * 6;
        body<64, 1, 0>(r % NB, r / NB, a.emb, a.idx[0], a.wi[0], a.bi[0], a.wo[0], a.bo[0], a.om[0], a.oi[0], buf);
    }
}

// ---- fallback (ws too small): on-the-fly f32 path, row-major weights ----
template<int D, int A, int MINW>
__global__ __launch_bounds__(256, MINW)
void msg_kernel(const float* __restrict__ embv,
                const int* __restrict__ idx,
                const float* __restrict__ wiv, const float* __restrict__ bi,
                const float* __restrict__ wov, const float* __restrict__ bo,
                float* __restrict__ out_msgs, float* __restrict__ out_idx)
{
    constexpr int DP = D + 8;
    constexpr int CT = D / 64;
    constexpr int KS = D / 32;
    constexpr int RC = D / 8;
    __shared__ __hip_bfloat16 buf[TM][DP];

    const int g    = blockIdx.y;
    const int f0   = blockIdx.x * TM;
    const int tid  = threadIdx.x;
    const int lane = tid & 63;
    const int w    = tid >> 6;
    const long gFA = (long)g * NF * A;
    const int valid = min(TM, NF - f0);

    {
        const int* idx_g = idx + gFA + (long)f0 * A;
        #pragma unroll
        for (int c = tid; c < TM * RC; c += 256) {
            int r = c / RC;
            int i = (c - r * RC) * 8;
            bf16x8 v = (bf16x8)0;
            if (r < valid) {
                int node = idx_g[r * A + (i >> 6)];
                const float4* s = (const float4*)(embv + (long)node * 64 + (i & 63));
                v = cvt8(s[0], s[1]);
            }
            *(bf16x8*)(&buf[r][i]) = v;
        }
        if (tid < valid * A) out_idx[gFA + (long)f0 * A + tid] = (float)idx_g[tid];
    }
    __syncthreads();

    const int ar = lane & 15;
    const int kg = lane >> 4;
    const int c0 = w * (D / 4);
    const long wbase = (long)g * D * D;

    f32x4 acc[4][CT];
    #pragma unroll
    for (int rt = 0; rt < 4; rt++)
        #pragma unroll
        for (int ct = 0; ct < CT; ct++) acc[rt][ct] = (f32x4)0.0f;

    #pragma unroll
    for (int ks = 0; ks < KS; ks++) {
        const int kk = ks * 32;
        bf16x8 xb[4];
        #pragma unroll
        for (int rt = 0; rt < 4; rt++) xb[rt] = *(const bf16x8*)(&buf[rt * 16 + ar][kk + kg * 8]);
        #pragma unroll
        for (int ct = 0; ct < CT; ct++) {
            const float4* bp = (const float4*)(wiv + wbase + (long)(c0 + ct * 16 + ar) * D + kk + kg * 8);
            bf16x8 wf = cvt8(bp[0], bp[1]);
            #pragma unroll
            for (int rt = 0; rt < 4; rt++)
                acc[rt][ct] = __builtin_amdgcn_mfma_f32_16x16x32_bf16(wf, xb[rt], acc[rt][ct], 0, 0, 0);
        }
    }

    bf16x4 res[4][CT];
    #pragma unroll
    for (int ct = 0; ct < CT; ct++) {
        const int cb = c0 + ct * 16 + kg * 4;
        #pragma unroll
        for (int rt = 0; rt < 4; rt++)
            res[rt][ct] = *(const bf16x4*)(&buf[rt * 16 + ar][cb]);
    }
    __syncthreads();

    #pragma unroll
    for (int ct = 0; ct < CT; ct++) {
        const int cb = c0 + ct * 16 + kg * 4;
        const float4 bi4 = *(const float4*)(bi + g * D + cb);
        #pragma unroll
        for (int rt = 0; rt < 4; rt++) {
            bf16x4 hv;
            hv[0] = bfs(mish_f(acc[rt][ct][0] + bi4.x));
            hv[1] = bfs(mish_f(acc[rt][ct][1] + bi4.y));
            hv[2] = bfs(mish_f(acc[rt][ct][2] + bi4.z));
            hv[3] = bfs(mish_f(acc[rt][ct][3] + bi4.w));
            *(bf16x4*)(&buf[rt * 16 + ar][cb]) = hv;
        }
    }
    __syncthreads();

    #pragma unroll
    for (int rt = 0; rt < 4; rt++)
        #pragma unroll
        for (int ct = 0; ct < CT; ct++) acc[rt][ct] = (f32x4)0.0f;

    #pragma unroll
    for (int ks = 0; ks < KS; ks++) {
        const int kk = ks * 32;
        bf16x8 hb[4];
        #pragma unroll
        for (int rt = 0; rt < 4; rt++) hb[rt] = *(const bf16x8*)(&buf[rt * 16 + ar][kk + kg * 8]);
        #pragma unroll
        for (int ct = 0; ct < CT; ct++) {
            const float4* bp = (const float4*)(wov + wbase + (long)(c0 + ct * 16 + ar) * D + kk + kg * 8);
            bf16x8 wf = cvt8(bp[0], bp[1]);
            #pragma unroll
            for (int rt = 0; rt < 4; rt++)
                acc[rt][ct] = __builtin_amdgcn_mfma_f32_16x16x32_bf16(wf, hb[rt], acc[rt][ct], 0, 0, 0);
        }
    }

    {
        float* ob = out_msgs + (gFA + (long)f0 * A) * 64;
        #pragma unroll
        for (int ct = 0; ct < CT; ct++) {
            const int cb = c0 + ct * 16 + kg * 4;
            const float4 bo4 = *(const float4*)(bo + g * D + cb);
            #pragma unroll
            for (int rt = 0; rt < 4; rt++) {
                const int r = rt * 16 + ar;
                float4 o;
                o.x = acc[rt][ct][0] + bo4.x + b2f(res[rt][ct][0]);
                o.y = acc[rt][ct][1] + bo4.y + b2f(res[rt][ct][1]);
                o.z = acc[rt][ct][2] + bo4.z + b2f(res[rt][ct][2]);
                o.w = acc[rt][ct][3] + bo4.w + b2f(res[rt][ct][3]);
                if (r < valid) *(float4*)(ob + (long)r * D + cb) = o;
            }
        }
    }
}

extern "C" void kernel_launch(void* const* d_in, const int* in_sizes, int n_in,
                              void* d_out, int out_size, void* d_ws, size_t ws_size,
                              hipStream_t stream) {
    const float* emb_f = (const float*)d_in[0];
    const int Gs[4] = {2, 3, 2, 1};
    const int Ds[4] = {64, 128, 192, 256};

    const int*   idx_a[4];
    const float *wi_f[4], *bi_f[4], *wo_f[4], *bo_f[4];
    for (int k = 0; k < 4; k++) {
        idx_a[k] = (const int*)d_in[1 + 5 * k];
        wi_f[k]  = (const float*)d_in[2 + 5 * k];
        bi_f[k]  = (const float*)d_in[3 + 5 * k];
        wo_f[k]  = (const float*)d_in[4 + 5 * k];
        bo_f[k]  = (const float*)d_in[5 + 5 * k];
    }

    float* out = (float*)d_out;
    const long MSG_ELEMS = 115200000L;
    const long rowOff[4] = {0, 200000, 800000, 1400000};
    float* om[4]; float* oi[4];
    for (int k = 0; k < 4; k++) {
        om[k] = out + rowOff[k] * 64;
        oi[k] = out + MSG_ELEMS + rowOff[k];
    }

    const long EMB_ELEMS = 6400000L;
    long wPre[9]; wPre[0] = 0;
    int  wD[8];
    for (int k = 0; k < 4; k++) {
        long we = (long)Gs[k] * Ds[k] * Ds[k];
        wPre[2 * k + 1] = wPre[2 * k] + we;
        wPre[2 * k + 2] = wPre[2 * k + 1] + we;
        wD[2 * k] = Ds[k]; wD[2 * k + 1] = Ds[k];
    }
    const long NEED = (EMB_ELEMS + wPre[8]) * 2;

    if (ws_size >= (size_t)NEED) {
        __hip_bfloat16* emb_b = (__hip_bfloat16*)d_ws;
        __hip_bfloat16* w_b   = emb_b + EMB_ELEMS;

        CvtA ca;
        for (int k = 0; k < 4; k++) { ca.src[2 * k] = wi_f[k]; ca.src[2 * k + 1] = wo_f[k]; }
        for (int j = 0; j < 9; j++) ca.pre[j] = wPre[j];
        for (int j = 0; j < 8; j++) ca.Dv[j] = wD[j];
        ca.emb = emb_f;
        ca.embElems = EMB_ELEMS;
        long totChunks = (EMB_ELEMS + wPre[8]) / 8;
        cvt_all<<<dim3((totChunks + 255) / 256), dim3(256), 0, stream>>>(ca, emb_b);

        KArgs a;
        a.emb = emb_b;
        for (int k = 0; k < 4; k++) {
            a.idx[k] = idx_a[k];
            a.wi[k] = w_b + wPre[2 * k];
            a.wo[k] = w_b + wPre[2 * k + 1];
            a.bi[k] = bi_f[k];
            a.bo[k] = bo_f[k];
            a.om[k] = om[k];
            a.oi[k] = oi[k];
        }
        fused_kernel<<<dim3(NB * 8), dim3(256), 0, stream>>>(a);
    } else {
        msg_kernel<64, 1, 4><<<dim3(NB, 2), 256, 0, stream>>>(
            emb_f, idx_a[0], wi_f[0], bi_f[0], wo_f[0], bo_f[0], om[0], oi[0]);
        msg_kernel<128, 2, 4><<<dim3(NB, 3), 256, 0, stream>>>(
            emb_f, idx_a[1], wi_f[1], bi_f[1], wo_f[1], bo_f[1], om[1], oi[1]);
        msg_kernel<192, 3, 4><<<dim3(NB, 2), 256, 0, stream>>>(
            emb_f, idx_a[2], wi_f[2], bi_f[2], wo_f[2], bo_f[2], om[2], oi[2]);
        msg_kernel<256, 4, 3><<<dim3(NB, 1), 256, 0, stream>>>(
            emb_f, idx_a[3], wi_f[3], bi_f[3], wo_f[3], bo_f[3], om[3], oi[3]);
    }
}